// Round 5
// baseline (893.958 us; speedup 1.0000x reference)
//
#include <hip/hip_runtime.h>
#include <hip/hip_bf16.h>
#include <math.h>

static constexpr int kN = 8192;
static constexpr int kD = 384;
static constexpr int kND = kN * kD;

typedef __attribute__((ext_vector_type(8))) short short8;
typedef __attribute__((ext_vector_type(4))) float f32x4;

// ---- bf16 helpers (bit-exact RNE) ----
__device__ __forceinline__ ushort f2bf(float f) {
  union { float f; unsigned int i; } cv; cv.f = f;
  unsigned int lsb = (cv.i >> 16) & 1u;
  unsigned int r = cv.i + 0x7fffu + lsb;
  return (ushort)(r >> 16);
}
__device__ __forceinline__ float bf2f(ushort u) {
  union { unsigned int i; float f; } cv; cv.i = ((unsigned int)u) << 16;
  return cv.f;
}
__device__ __forceinline__ f32x4 mfma_bf16(short8 a, short8 b, f32x4 c) {
  return __builtin_amdgcn_mfma_f32_16x16x32_bf16(a, b, c, 0, 0, 0);
}
// 3-term compensated product: ah*bh + ah*bl + al*bh  (error ~2^-16)
__device__ __forceinline__ f32x4 mfma3(short8 ah, short8 al, short8 bh, short8 bl, f32x4 c) {
  c = mfma_bf16(ah, bh, c);
  c = mfma_bf16(ah, bl, c);
  c = mfma_bf16(al, bh, c);
  return c;
}

// ---------------------------------------------------------------------------
// GEMM: Y = X[kN][kD] @ W[kD][kD]^T.
// MODE 0: fp32 out. MODE 1: bf16 hi/lo out. MODE 2: bf16 hi/lo transposed.
// ---------------------------------------------------------------------------
template <int MODE>
__global__ __launch_bounds__(256) void gemm_xwT(
    const float* __restrict__ X, const float* __restrict__ W,
    float* __restrict__ Y, ushort* __restrict__ Yh, ushort* __restrict__ Yl)
{
  __shared__ float Xs[64][33];
  __shared__ float WsT[32][68];
  const int tid = threadIdx.x;
  const int tx = tid & 15;
  const int ty = tid >> 4;
  const int i0 = blockIdx.x * 64;
  const int j0 = blockIdx.y * 64;
  float acc[4][4] = {};

  for (int k0 = 0; k0 < kD; k0 += 32) {
#pragma unroll
    for (int s = 0; s < 2; ++s) {
      const int f = tid + 256 * s;
      const int row = f >> 3;
      const int c4 = (f & 7) * 4;
      const float4 v = *reinterpret_cast<const float4*>(
          &X[(size_t)(i0 + row) * kD + k0 + c4]);
      Xs[row][c4 + 0] = v.x; Xs[row][c4 + 1] = v.y;
      Xs[row][c4 + 2] = v.z; Xs[row][c4 + 3] = v.w;
    }
#pragma unroll
    for (int s = 0; s < 2; ++s) {
      const int f = tid + 256 * s;
      const int col = f >> 3;
      const int c4 = (f & 7) * 4;
      const float4 v = *reinterpret_cast<const float4*>(
          &W[(size_t)(j0 + col) * kD + k0 + c4]);
      WsT[c4 + 0][col] = v.x; WsT[c4 + 1][col] = v.y;
      WsT[c4 + 2][col] = v.z; WsT[c4 + 3][col] = v.w;
    }
    __syncthreads();
#pragma unroll
    for (int kk = 0; kk < 32; ++kk) {
      const float4 b = *reinterpret_cast<const float4*>(&WsT[kk][tx * 4]);
      const float a0 = Xs[ty * 4 + 0][kk];
      const float a1 = Xs[ty * 4 + 1][kk];
      const float a2 = Xs[ty * 4 + 2][kk];
      const float a3 = Xs[ty * 4 + 3][kk];
      acc[0][0] += a0 * b.x; acc[0][1] += a0 * b.y; acc[0][2] += a0 * b.z; acc[0][3] += a0 * b.w;
      acc[1][0] += a1 * b.x; acc[1][1] += a1 * b.y; acc[1][2] += a1 * b.z; acc[1][3] += a1 * b.w;
      acc[2][0] += a2 * b.x; acc[2][1] += a2 * b.y; acc[2][2] += a2 * b.z; acc[2][3] += a2 * b.w;
      acc[3][0] += a3 * b.x; acc[3][1] += a3 * b.y; acc[3][2] += a3 * b.z; acc[3][3] += a3 * b.w;
    }
    __syncthreads();
  }
  if constexpr (MODE == 0) {
#pragma unroll
    for (int r = 0; r < 4; ++r) {
      float4 v;
      v.x = acc[r][0]; v.y = acc[r][1]; v.z = acc[r][2]; v.w = acc[r][3];
      *reinterpret_cast<float4*>(
          &Y[(size_t)(i0 + ty * 4 + r) * kD + j0 + tx * 4]) = v;
    }
  } else if constexpr (MODE == 1) {
#pragma unroll
    for (int r = 0; r < 4; ++r) {
      ushort4 h, l;
      ushort* hp = &h.x; ushort* lp = &l.x;
#pragma unroll
      for (int c = 0; c < 4; ++c) {
        const float f = acc[r][c];
        const ushort hh = f2bf(f);
        hp[c] = hh;
        lp[c] = f2bf(f - bf2f(hh));
      }
      const int oi = (i0 + ty * 4 + r) * kD + j0 + tx * 4;
      *reinterpret_cast<ushort4*>(&Yh[oi]) = h;
      *reinterpret_cast<ushort4*>(&Yl[oi]) = l;
    }
  } else {
#pragma unroll
    for (int c = 0; c < 4; ++c) {
      ushort4 h, l;
      ushort* hp = &h.x; ushort* lp = &l.x;
#pragma unroll
      for (int r = 0; r < 4; ++r) {
        const float f = acc[r][c];
        const ushort hh = f2bf(f);
        hp[r] = hh;
        lp[r] = f2bf(f - bf2f(hh));
      }
      const int oi = (j0 + tx * 4 + c) * kN + i0 + ty * 4;
      *reinterpret_cast<ushort4*>(&Yh[oi]) = h;
      *reinterpret_cast<ushort4*>(&Yl[oi]) = l;
    }
  }
}

// ---------------------------------------------------------------------------
// MFMA flash attention v5: BM=32 q-rows/block, 512 threads (8 waves),
// 2 barriers/tile, grid (2,256)=512 blocks -> 2 blocks/CU, 4 waves/SIMD.
// S^T = mfma3(K,Q): wave w owns keys [16w,16w+16), all 32 q-rows (qt=0,1).
//   sacc[qt]: key=16w+4*hi4+r (row), qrow=16qt+l15 (col).
// Q-hi AND Q-lo staged once in LDS; K hi/lo direct from global (L2).
// P stored hi-only in LDS; PV = ph*vh + ph*vl with V-frags direct from
// global VT (wave w owns d-cols [48w,48w+48) -> private, no barrier).
// LDS: Qh 24.5K | Ql 24.5K | P 8.5K | MLB 2K = ~60K -> 2 blocks/CU.
// ---------------------------------------------------------------------------
static constexpr int SPLITf = 2;
static constexpr int KEYSf = kN / SPLITf;  // 4096 -> 32 tiles of 128

static constexpr int OFF_QH = 0;       // ushort offsets into LDSU
static constexpr int OFF_QL = 12544;   // 32*392
static constexpr int OFF_P  = 25088;   // + 32*392

__global__ __launch_bounds__(512, 4) void flash_mfma(
    const ushort* __restrict__ Qh, const ushort* __restrict__ Ql,
    const ushort* __restrict__ Kh, const ushort* __restrict__ Kl,
    const ushort* __restrict__ VTh, const ushort* __restrict__ VTl,
    float* __restrict__ Opart, float* __restrict__ ml)
{
  __shared__ ushort LDSU[29440];   // 58880 B
  __shared__ float MLB[512];       // m: [0,256), l: [256,512)

  const int tid = threadIdx.x;
  const int w = tid >> 6;
  const int lane = tid & 63;
  const int l15 = lane & 15;
  const int hi4 = lane >> 4;
  const int sp = blockIdx.x;
  const int i0 = blockIdx.y * 32;
  const int kg0 = sp * KEYSf;

  // ---- stage Q-hi + Q-lo once: 32 rows, stride 392 ushorts ----
  {
    const int row = tid >> 4;            // 32 rows, 16 threads each
    const int sg = (tid & 15) * 24;      // 24 ushorts = 3 x uint4
    const ushort* sh = Qh + (size_t)(i0 + row) * kD + sg;
    const ushort* sl = Ql + (size_t)(i0 + row) * kD + sg;
    ushort* dh = LDSU + OFF_QH + row * 392 + sg;
    ushort* dl = LDSU + OFF_QL + row * 392 + sg;
#pragma unroll
    for (int u = 0; u < 3; ++u) {
      *reinterpret_cast<uint4*>(dh + 8 * u) =
          *reinterpret_cast<const uint4*>(sh + 8 * u);
      *reinterpret_cast<uint4*>(dl + 8 * u) =
          *reinterpret_cast<const uint4*>(sl + 8 * u);
    }
  }

  const f32x4 zf = {0.f, 0.f, 0.f, 0.f};
  f32x4 o[2][3];
#pragma unroll
  for (int qt = 0; qt < 2; ++qt)
#pragma unroll
    for (int c = 0; c < 3; ++c) o[qt][c] = zf;
  float m_run[2], l_run[2];
#pragma unroll
  for (int qt = 0; qt < 2; ++qt) { m_run[qt] = -INFINITY; l_run[qt] = 0.f; }

  __syncthreads();

  for (int kb = 0; kb < KEYSf / 128; ++kb) {
    const int kg = kg0 + kb * 128;

    // ---- S phase: K hi/lo direct from global, Q hi/lo from LDS ----
    f32x4 sacc[2];
    sacc[0] = zf; sacc[1] = zf;
    const size_t kbase = (size_t)(kg + 16 * w + l15) * kD + 8 * hi4;
#pragma unroll 6
    for (int ks = 0; ks < 12; ++ks) {
      const int d0 = 32 * ks;
      const short8 kh = *reinterpret_cast<const short8*>(Kh + kbase + d0);
      const short8 kl = *reinterpret_cast<const short8*>(Kl + kbase + d0);
#pragma unroll
      for (int qt = 0; qt < 2; ++qt) {
        const int qoff = (16 * qt + l15) * 392 + d0 + 8 * hi4;
        const short8 qh = *reinterpret_cast<const short8*>(LDSU + OFF_QH + qoff);
        const short8 ql = *reinterpret_cast<const short8*>(LDSU + OFF_QL + qoff);
        sacc[qt] = mfma3(kh, kl, qh, ql, sacc[qt]);
      }
    }

    // ---- online softmax ----
    float mt2[2];
#pragma unroll
    for (int qt = 0; qt < 2; ++qt) {
      float mt = fmaxf(fmaxf(sacc[qt][0], sacc[qt][1]),
                       fmaxf(sacc[qt][2], sacc[qt][3]));
      mt = fmaxf(mt, __shfl_xor(mt, 16, 64));
      mt = fmaxf(mt, __shfl_xor(mt, 32, 64));
      mt2[qt] = mt;
    }
    if (lane < 16) {
#pragma unroll
      for (int qt = 0; qt < 2; ++qt) MLB[w * 32 + qt * 16 + l15] = mt2[qt];
    }
    __syncthreads();  // B1
    float sc[2];
#pragma unroll
    for (int qt = 0; qt < 2; ++qt) {
      float Mt = MLB[qt * 16 + l15];
#pragma unroll
      for (int w2 = 1; w2 < 8; ++w2)
        Mt = fmaxf(Mt, MLB[w2 * 32 + qt * 16 + l15]);
      const float mnew = fmaxf(m_run[qt], Mt);
      sc[qt] = __expf(m_run[qt] - mnew);
      m_run[qt] = mnew;
      const float p0 = __expf(sacc[qt][0] - mnew);
      const float p1 = __expf(sacc[qt][1] - mnew);
      const float p2 = __expf(sacc[qt][2] - mnew);
      const float p3 = __expf(sacc[qt][3] - mnew);
      float ls = (p0 + p1) + (p2 + p3);
      ls += __shfl_xor(ls, 16, 64);
      ls += __shfl_xor(ls, 32, 64);
      if (lane < 16) MLB[256 + w * 32 + qt * 16 + l15] = ls;
      // pack P -> bf16 hi only, one b64 write
      uint2 HH;
      HH.x = (unsigned int)f2bf(p0) | ((unsigned int)f2bf(p1) << 16);
      HH.y = (unsigned int)f2bf(p2) | ((unsigned int)f2bf(p3) << 16);
      const int pi = (16 * qt + l15) * 136 + 16 * w + 4 * hi4;
      *reinterpret_cast<uint2*>(LDSU + OFF_P + pi) = HH;
      // rescale O (row of o = qrow 16qt+4*hi4+r)
#pragma unroll
      for (int r = 0; r < 4; ++r) {
        const float scr_ = __shfl(sc[qt], 4 * hi4 + r, 64);
#pragma unroll
        for (int c = 0; c < 3; ++c) o[qt][c][r] *= scr_;
      }
    }
    __syncthreads();  // B2: P + mlb_l ready
#pragma unroll
    for (int qt = 0; qt < 2; ++qt) {
      float acc = MLB[256 + qt * 16 + l15];
#pragma unroll
      for (int w2 = 1; w2 < 8; ++w2) acc += MLB[256 + w2 * 32 + qt * 16 + l15];
      l_run[qt] = l_run[qt] * sc[qt] + acc;
    }

    // ---- PV: barrier-free; wave w owns d-cols [48w, 48w+48) ----
#pragma unroll
    for (int ksv = 0; ksv < 4; ++ksv) {
      short8 pf0 = *reinterpret_cast<const short8*>(
          LDSU + OFF_P + (l15)*136 + 32 * ksv + 8 * hi4);
      short8 pf1 = *reinterpret_cast<const short8*>(
          LDSU + OFF_P + (16 + l15) * 136 + 32 * ksv + 8 * hi4);
#pragma unroll
      for (int c = 0; c < 3; ++c) {
        const size_t g =
            (size_t)(48 * w + 16 * c + l15) * kN + kg + 32 * ksv + 8 * hi4;
        const short8 vfh = *reinterpret_cast<const short8*>(VTh + g);
        const short8 vfl = *reinterpret_cast<const short8*>(VTl + g);
        o[0][c] = mfma_bf16(pf0, vfh, o[0][c]);
        o[0][c] = mfma_bf16(pf0, vfl, o[0][c]);
        o[1][c] = mfma_bf16(pf1, vfh, o[1][c]);
        o[1][c] = mfma_bf16(pf1, vfl, o[1][c]);
      }
    }
  }

  // ---- write unnormalized partials + (m,l); waves own disjoint d-cols ----
#pragma unroll
  for (int qt = 0; qt < 2; ++qt)
#pragma unroll
    for (int c = 0; c < 3; ++c)
#pragma unroll
      for (int r = 0; r < 4; ++r)
        Opart[(size_t)sp * kND + (i0 + 16 * qt + 4 * hi4 + r) * kD +
              48 * w + 16 * c + l15] = o[qt][c][r];
  if (w == 0 && lane < 16) {
#pragma unroll
    for (int qt = 0; qt < 2; ++qt) {
      const int mi = (sp * kN + i0 + 16 * qt + l15) * 2;
      ml[mi] = m_run[qt];
      ml[mi + 1] = l_run[qt];
    }
  }
}

// ---------------------------------------------------------------------------
// Merge 2 key-split partials
// ---------------------------------------------------------------------------
__global__ __launch_bounds__(256) void merge_kernel(
    const float* __restrict__ Opart, const float* __restrict__ ml,
    float* __restrict__ O)
{
  const size_t idx = (size_t)blockIdx.x * 256 + threadIdx.x;
  const size_t i = idx / kD;
  const float m0 = ml[i * 2];
  const float l0 = ml[i * 2 + 1];
  const float m1 = ml[((size_t)kN + i) * 2];
  const float l1 = ml[((size_t)kN + i) * 2 + 1];
  const float m = fmaxf(m0, m1);
  const float e0 = expf(m0 - m);
  const float e1 = expf(m1 - m);
  const float inv = 1.0f / (e0 * l0 + e1 * l1);
  O[idx] = (e0 * Opart[idx] + e1 * Opart[(size_t)kND + idx]) * inv;
}

// ---------------------------------------------------------------------------
// Layer-2 helpers (only last row of layer 2 needed)
// ---------------------------------------------------------------------------
__global__ __launch_bounds__(64) void qrow_kernel(
    const float* __restrict__ h1, const float* __restrict__ Wq,
    float* __restrict__ q2)
{
  const int j = blockIdx.x;
  const int lane = threadIdx.x;
  const float* hr = h1 + (size_t)(kN - 1) * kD;
  float acc = 0.f;
  for (int d = lane; d < kD; d += 64) acc += hr[d] * Wq[(size_t)j * kD + d];
#pragma unroll
  for (int off = 32; off > 0; off >>= 1) acc += __shfl_xor(acc, off, 64);
  if (lane == 0) q2[j] = acc;
}

__global__ __launch_bounds__(256) void logits_kernel(
    const float* __restrict__ Kt2, const float* __restrict__ q2,
    float* __restrict__ lg)
{
  const int wave = threadIdx.x >> 6;
  const int lane = threadIdx.x & 63;
  const int j = blockIdx.x * 4 + wave;
  float acc = 0.f;
#pragma unroll
  for (int t = 0; t < kD / 64; ++t) {
    const int d = lane + t * 64;
    acc += Kt2[(size_t)j * kD + d] * q2[d];
  }
#pragma unroll
  for (int off = 32; off > 0; off >>= 1) acc += __shfl_xor(acc, off, 64);
  if (lane == 0) lg[j] = acc;
}

__global__ __launch_bounds__(1024) void smax_kernel(
    const float* __restrict__ lg, float* __restrict__ wgt)
{
  __shared__ float red[16];
  const int t = threadIdx.x;
  const int wave = t >> 6;
  const int lane = t & 63;
  float v[8];
  float mx = -INFINITY;
#pragma unroll
  for (int s = 0; s < 8; ++s) {
    v[s] = lg[t + 1024 * s];
    mx = fmaxf(mx, v[s]);
  }
#pragma unroll
  for (int off = 32; off > 0; off >>= 1) mx = fmaxf(mx, __shfl_xor(mx, off, 64));
  if (lane == 0) red[wave] = mx;
  __syncthreads();
  if (t == 0) {
    float m = red[0];
    for (int i = 1; i < 16; ++i) m = fmaxf(m, red[i]);
    red[0] = m;
  }
  __syncthreads();
  const float m = red[0];
  __syncthreads();
  float sum = 0.f;
#pragma unroll
  for (int s = 0; s < 8; ++s) {
    v[s] = expf(v[s] - m);
    sum += v[s];
  }
#pragma unroll
  for (int off = 32; off > 0; off >>= 1) sum += __shfl_xor(sum, off, 64);
  if (lane == 0) red[wave] = sum;
  __syncthreads();
  if (t == 0) {
    float S = 0.f;
    for (int i = 0; i < 16; ++i) S += red[i];
    red[0] = S;
  }
  __syncthreads();
  const float invS = 1.0f / red[0];
#pragma unroll
  for (int s = 0; s < 8; ++s) wgt[t + 1024 * s] = v[s] * invS;
}

__global__ __launch_bounds__(384) void wsum_kernel(
    const float* __restrict__ wgt, const float* __restrict__ Vt2,
    float* __restrict__ part)
{
  __shared__ float wl[256];
  const int b = blockIdx.x;
  const int t = threadIdx.x;
  if (t < 256) wl[t] = wgt[b * 256 + t];
  __syncthreads();
  const float* Vp = Vt2 + (size_t)b * 256 * kD;
  float acc = 0.f;
  for (int j = 0; j < 256; ++j) acc += wl[j] * Vp[(size_t)j * kD + t];
  part[b * kD + t] = acc;
}

__global__ __launch_bounds__(384) void final_kernel(
    const float* __restrict__ part, const float* __restrict__ ffws,
    float* __restrict__ out)
{
  __shared__ float red[6];
  const int t = threadIdx.x;
  const int wave = t >> 6;
  const int lane = t & 63;
  float z = 0.f;
#pragma unroll
  for (int b = 0; b < 32; ++b) z += part[b * kD + t];
  float val = z * ffws[t];
#pragma unroll
  for (int off = 32; off > 0; off >>= 1) val += __shfl_xor(val, off, 64);
  if (lane == 0) red[wave] = val;
  __syncthreads();
  if (t == 0) {
    float s = red[0];
    for (int i = 1; i < 6; ++i) s += red[i];
    out[0] = 1.0f / (1.0f + expf(-s));
  }
}

// ---------------------------------------------------------------------------
extern "C" void kernel_launch(void* const* d_in, const int* in_sizes, int n_in,
                              void* d_out, int out_size, void* d_ws, size_t ws_size,
                              hipStream_t stream) {
  const float* x    = (const float*)d_in[0];
  const float* Wq   = (const float*)d_in[1];
  const float* Wk   = (const float*)d_in[2];
  const float* Wv   = (const float*)d_in[3];
  const float* ffws = (const float*)d_in[4];
  float* out = (float*)d_out;
  char* wsb = (char*)d_ws;

  ushort* Qh  = (ushort*)wsb;
  ushort* Ql  = Qh + kND;
  ushort* Kh  = Ql + kND;
  ushort* Kl  = Kh + kND;
  ushort* VTh = Kl + kND;
  ushort* VTl = VTh + kND;
  float* Opart = (float*)(wsb + 6 * (size_t)kND * 2);
  float* ml    = Opart + 2 * (size_t)kND;
  // phase-2 overlays (flash buffers dead):
  float* Kt2 = (float*)wsb;                         // over Qh/Ql
  float* Vt2 = (float*)(wsb + 2 * (size_t)kND * 2); // over Kh/Kl
  float* h1  = (float*)(wsb + 4 * (size_t)kND * 2); // over VTh/VTl
  float* q2  = (float*)(wsb + 6 * (size_t)kND * 2); // over Opart
  float* lg  = q2 + kD;
  float* wgt = lg + kN;
  float* part = wgt + kN;

  const dim3 gg(kN / 64, kD / 64);
  gemm_xwT<1><<<gg, 256, 0, stream>>>(x, Wq, nullptr, Qh, Ql);
  gemm_xwT<1><<<gg, 256, 0, stream>>>(x, Wk, nullptr, Kh, Kl);
  gemm_xwT<2><<<gg, 256, 0, stream>>>(x, Wv, nullptr, VTh, VTl);
  flash_mfma<<<dim3(SPLITf, kN / 32), 512, 0, stream>>>(
      Qh, Ql, Kh, Kl, VTh, VTl, Opart, ml);
  merge_kernel<<<(kN * kD) / 256, 256, 0, stream>>>(Opart, ml, h1);
  gemm_xwT<0><<<gg, 256, 0, stream>>>(h1, Wk, Kt2, nullptr, nullptr);
  gemm_xwT<0><<<gg, 256, 0, stream>>>(h1, Wv, Vt2, nullptr, nullptr);
  qrow_kernel<<<kD, 64, 0, stream>>>(h1, Wq, q2);
  logits_kernel<<<kN / 4, 256, 0, stream>>>(Kt2, q2, lg);
  smax_kernel<<<1, 1024, 0, stream>>>(lg, wgt);
  wsum_kernel<<<32, 384, 0, stream>>>(wgt, Vt2, part);
  final_kernel<<<1, 384, 0, stream>>>(part, ffws, out);
}

// Round 6
// 671.561 us; speedup vs baseline: 1.3312x; 1.3312x over previous
//
#include <hip/hip_runtime.h>
#include <hip/hip_bf16.h>
#include <math.h>

static constexpr int kN = 8192;
static constexpr int kD = 384;
static constexpr int kND = kN * kD;

typedef __attribute__((ext_vector_type(8))) short short8;
typedef __attribute__((ext_vector_type(4))) float f32x4;
typedef __attribute__((ext_vector_type(4))) unsigned int u32x4;

// ---- bf16 helpers (bit-exact RNE) ----
__device__ __forceinline__ ushort f2bf(float f) {
  union { float f; unsigned int i; } cv; cv.f = f;
  unsigned int lsb = (cv.i >> 16) & 1u;
  unsigned int r = cv.i + 0x7fffu + lsb;
  return (ushort)(r >> 16);
}
__device__ __forceinline__ float bf2f(ushort u) {
  union { unsigned int i; float f; } cv; cv.i = ((unsigned int)u) << 16;
  return cv.f;
}
__device__ __forceinline__ f32x4 mfma_bf16(short8 a, short8 b, f32x4 c) {
  return __builtin_amdgcn_mfma_f32_16x16x32_bf16(a, b, c, 0, 0, 0);
}
// 3-term compensated product: ah*bh + ah*bl + al*bh  (error ~2^-16)
__device__ __forceinline__ f32x4 mfma3(short8 ah, short8 al, short8 bh, short8 bl, f32x4 c) {
  c = mfma_bf16(ah, bh, c);
  c = mfma_bf16(ah, bl, c);
  c = mfma_bf16(al, bh, c);
  return c;
}

// Opart store/load helpers (nontemporal; bf16 variant rounds)
__device__ __forceinline__ void storeO(float* p, float v) {
  __builtin_nontemporal_store(v, p);
}
__device__ __forceinline__ void storeO(ushort* p, float v) {
  __builtin_nontemporal_store(f2bf(v), p);
}
__device__ __forceinline__ float loadO(const float* p) {
  return __builtin_nontemporal_load(p);
}
__device__ __forceinline__ float loadO(const ushort* p) {
  return bf2f(__builtin_nontemporal_load(p));
}

// ---------------------------------------------------------------------------
// GEMM: Y = X[kN][kD] @ W[kD][kD]^T.
// MODE 0: fp32 out. MODE 1: bf16 hi/lo out. MODE 2: bf16 hi/lo transposed.
// ---------------------------------------------------------------------------
template <int MODE>
__global__ __launch_bounds__(256) void gemm_xwT(
    const float* __restrict__ X, const float* __restrict__ W,
    float* __restrict__ Y, ushort* __restrict__ Yh, ushort* __restrict__ Yl)
{
  __shared__ float Xs[64][33];
  __shared__ float WsT[32][68];
  const int tid = threadIdx.x;
  const int tx = tid & 15;
  const int ty = tid >> 4;
  const int i0 = blockIdx.x * 64;
  const int j0 = blockIdx.y * 64;
  float acc[4][4] = {};

  for (int k0 = 0; k0 < kD; k0 += 32) {
#pragma unroll
    for (int s = 0; s < 2; ++s) {
      const int f = tid + 256 * s;
      const int row = f >> 3;
      const int c4 = (f & 7) * 4;
      const float4 v = *reinterpret_cast<const float4*>(
          &X[(size_t)(i0 + row) * kD + k0 + c4]);
      Xs[row][c4 + 0] = v.x; Xs[row][c4 + 1] = v.y;
      Xs[row][c4 + 2] = v.z; Xs[row][c4 + 3] = v.w;
    }
#pragma unroll
    for (int s = 0; s < 2; ++s) {
      const int f = tid + 256 * s;
      const int col = f >> 3;
      const int c4 = (f & 7) * 4;
      const float4 v = *reinterpret_cast<const float4*>(
          &W[(size_t)(j0 + col) * kD + k0 + c4]);
      WsT[c4 + 0][col] = v.x; WsT[c4 + 1][col] = v.y;
      WsT[c4 + 2][col] = v.z; WsT[c4 + 3][col] = v.w;
    }
    __syncthreads();
#pragma unroll
    for (int kk = 0; kk < 32; ++kk) {
      const float4 b = *reinterpret_cast<const float4*>(&WsT[kk][tx * 4]);
      const float a0 = Xs[ty * 4 + 0][kk];
      const float a1 = Xs[ty * 4 + 1][kk];
      const float a2 = Xs[ty * 4 + 2][kk];
      const float a3 = Xs[ty * 4 + 3][kk];
      acc[0][0] += a0 * b.x; acc[0][1] += a0 * b.y; acc[0][2] += a0 * b.z; acc[0][3] += a0 * b.w;
      acc[1][0] += a1 * b.x; acc[1][1] += a1 * b.y; acc[1][2] += a1 * b.z; acc[1][3] += a1 * b.w;
      acc[2][0] += a2 * b.x; acc[2][1] += a2 * b.y; acc[2][2] += a2 * b.z; acc[2][3] += a2 * b.w;
      acc[3][0] += a3 * b.x; acc[3][1] += a3 * b.y; acc[3][2] += a3 * b.z; acc[3][3] += a3 * b.w;
    }
    __syncthreads();
  }
  if constexpr (MODE == 0) {
#pragma unroll
    for (int r = 0; r < 4; ++r) {
      float4 v;
      v.x = acc[r][0]; v.y = acc[r][1]; v.z = acc[r][2]; v.w = acc[r][3];
      *reinterpret_cast<float4*>(
          &Y[(size_t)(i0 + ty * 4 + r) * kD + j0 + tx * 4]) = v;
    }
  } else if constexpr (MODE == 1) {
#pragma unroll
    for (int r = 0; r < 4; ++r) {
      ushort4 h, l;
      ushort* hp = &h.x; ushort* lp = &l.x;
#pragma unroll
      for (int c = 0; c < 4; ++c) {
        const float f = acc[r][c];
        const ushort hh = f2bf(f);
        hp[c] = hh;
        lp[c] = f2bf(f - bf2f(hh));
      }
      const int oi = (i0 + ty * 4 + r) * kD + j0 + tx * 4;
      *reinterpret_cast<ushort4*>(&Yh[oi]) = h;
      *reinterpret_cast<ushort4*>(&Yl[oi]) = l;
    }
  } else {
#pragma unroll
    for (int c = 0; c < 4; ++c) {
      ushort4 h, l;
      ushort* hp = &h.x; ushort* lp = &l.x;
#pragma unroll
      for (int r = 0; r < 4; ++r) {
        const float f = acc[r][c];
        const ushort hh = f2bf(f);
        hp[r] = hh;
        lp[r] = f2bf(f - bf2f(hh));
      }
      const int oi = (j0 + tx * 4 + c) * kN + i0 + ty * 4;
      *reinterpret_cast<ushort4*>(&Yh[oi]) = h;
      *reinterpret_cast<ushort4*>(&Yl[oi]) = l;
    }
  }
}

// ---------------------------------------------------------------------------
// MFMA flash attention v6: BM=64, 512 threads (8 waves), 2 barriers/tile.
// NSPLIT-way key split, XCD-pinned: sp = bid & (NSPLIT-1) so all blocks on
// one XCD share the same K/V slice (NSPLIT=8 -> 3.2 MB, fits 4 MB L2).
// S^T = mfma3(K,Q): wave w owns keys [16w,16w+16), all 64 q-rows (qt=0..3).
// Q hi+lo staged once in LDS (nontemporal global reads); K hi/lo direct from
// global (L2-resident); P hi-only in LDS; PV = ph*vh + ph*vl with V-frags
// direct from global VT (wave w owns d-cols [48w,48w+48)).
// Epilogue stores NORMALIZED per-split O (nontemporal) + (m,l).
// LDS: Qh 49K | Ql 49K | P 17.4K | MLB 4K = ~122K -> 1 block/CU, 8 waves.
// ---------------------------------------------------------------------------
static constexpr int OFF_QH = 0;       // ushort offsets into LDSU
static constexpr int OFF_QL = 25088;   // 64*392
static constexpr int OFF_P  = 50176;

template <int NSPLIT, typename OT>
__global__ __launch_bounds__(512, 2) void flash_mfma(
    const ushort* __restrict__ Qh, const ushort* __restrict__ Ql,
    const ushort* __restrict__ Kh, const ushort* __restrict__ Kl,
    const ushort* __restrict__ VTh, const ushort* __restrict__ VTl,
    OT* __restrict__ Opart, float* __restrict__ ml)
{
  constexpr int KEYS = kN / NSPLIT;
  __shared__ ushort LDSU[58880];   // 117760 B
  __shared__ float MLB[1024];      // m: [0,512), l: [512,1024)

  const int tid = threadIdx.x;
  const int w = tid >> 6;
  const int lane = tid & 63;
  const int l15 = lane & 15;
  const int hi4 = lane >> 4;
  const int bid = blockIdx.x;
  const int sp = bid & (NSPLIT - 1);
  const int i0 = (bid / NSPLIT) * 64;
  const int kg0 = sp * KEYS;

  // ---- stage Q-hi + Q-lo once (nontemporal: don't pollute L2) ----
  {
    const int row = tid >> 3;
    const int sg = (tid & 7) * 48;
    const u32x4* sh = reinterpret_cast<const u32x4*>(Qh + (size_t)(i0 + row) * kD + sg);
    const u32x4* sl = reinterpret_cast<const u32x4*>(Ql + (size_t)(i0 + row) * kD + sg);
    u32x4* dh = reinterpret_cast<u32x4*>(LDSU + OFF_QH + row * 392 + sg);
    u32x4* dl = reinterpret_cast<u32x4*>(LDSU + OFF_QL + row * 392 + sg);
#pragma unroll
    for (int u = 0; u < 6; ++u) {
      dh[u] = __builtin_nontemporal_load(sh + u);
      dl[u] = __builtin_nontemporal_load(sl + u);
    }
  }

  const f32x4 zf = {0.f, 0.f, 0.f, 0.f};
  f32x4 o[4][3];
#pragma unroll
  for (int qt = 0; qt < 4; ++qt)
#pragma unroll
    for (int c = 0; c < 3; ++c) o[qt][c] = zf;
  float m_run[4], l_run[4];
#pragma unroll
  for (int qt = 0; qt < 4; ++qt) { m_run[qt] = -INFINITY; l_run[qt] = 0.f; }

  __syncthreads();

  for (int kb = 0; kb < KEYS / 128; ++kb) {
    const int kg = kg0 + kb * 128;

    // ---- S phase: K hi/lo direct from global (L2), Q hi/lo from LDS ----
    f32x4 sacc[4];
#pragma unroll
    for (int qt = 0; qt < 4; ++qt) sacc[qt] = zf;
    const size_t kbase = (size_t)(kg + 16 * w + l15) * kD + 8 * hi4;
#pragma unroll 6
    for (int ks = 0; ks < 12; ++ks) {
      const int d0 = 32 * ks;
      const short8 kh = *reinterpret_cast<const short8*>(Kh + kbase + d0);
      const short8 kl = *reinterpret_cast<const short8*>(Kl + kbase + d0);
#pragma unroll
      for (int qt = 0; qt < 4; ++qt) {
        const int qoff = (16 * qt + l15) * 392 + d0 + 8 * hi4;
        const short8 qh = *reinterpret_cast<const short8*>(LDSU + OFF_QH + qoff);
        const short8 ql = *reinterpret_cast<const short8*>(LDSU + OFF_QL + qoff);
        sacc[qt] = mfma3(kh, kl, qh, ql, sacc[qt]);
      }
    }

    // ---- online softmax ----
    float mt4[4];
#pragma unroll
    for (int qt = 0; qt < 4; ++qt) {
      float mt = fmaxf(fmaxf(sacc[qt][0], sacc[qt][1]),
                       fmaxf(sacc[qt][2], sacc[qt][3]));
      mt = fmaxf(mt, __shfl_xor(mt, 16, 64));
      mt = fmaxf(mt, __shfl_xor(mt, 32, 64));
      mt4[qt] = mt;
    }
    if (lane < 16) {
#pragma unroll
      for (int qt = 0; qt < 4; ++qt) MLB[w * 64 + qt * 16 + l15] = mt4[qt];
    }
    __syncthreads();  // B1
    float sc[4];
#pragma unroll
    for (int qt = 0; qt < 4; ++qt) {
      float Mt = MLB[qt * 16 + l15];
#pragma unroll
      for (int w2 = 1; w2 < 8; ++w2)
        Mt = fmaxf(Mt, MLB[w2 * 64 + qt * 16 + l15]);
      const float mnew = fmaxf(m_run[qt], Mt);
      sc[qt] = __expf(m_run[qt] - mnew);
      m_run[qt] = mnew;
      const float p0 = __expf(sacc[qt][0] - mnew);
      const float p1 = __expf(sacc[qt][1] - mnew);
      const float p2 = __expf(sacc[qt][2] - mnew);
      const float p3 = __expf(sacc[qt][3] - mnew);
      float ls = (p0 + p1) + (p2 + p3);
      ls += __shfl_xor(ls, 16, 64);
      ls += __shfl_xor(ls, 32, 64);
      if (lane < 16) MLB[512 + w * 64 + qt * 16 + l15] = ls;
      // pack P -> bf16 hi only, one b64 write
      uint2 HH;
      HH.x = (unsigned int)f2bf(p0) | ((unsigned int)f2bf(p1) << 16);
      HH.y = (unsigned int)f2bf(p2) | ((unsigned int)f2bf(p3) << 16);
      const int pi = (16 * qt + l15) * 136 + 16 * w + 4 * hi4;
      *reinterpret_cast<uint2*>(LDSU + OFF_P + pi) = HH;
      // rescale O (row of o = qrow 16qt+4*hi4+r)
#pragma unroll
      for (int r = 0; r < 4; ++r) {
        const float scr_ = __shfl(sc[qt], 4 * hi4 + r, 64);
#pragma unroll
        for (int c = 0; c < 3; ++c) o[qt][c][r] *= scr_;
      }
    }
    __syncthreads();  // B2: P + mlb_l ready
#pragma unroll
    for (int qt = 0; qt < 4; ++qt) {
      float acc = MLB[512 + qt * 16 + l15];
#pragma unroll
      for (int w2 = 1; w2 < 8; ++w2) acc += MLB[512 + w2 * 64 + qt * 16 + l15];
      l_run[qt] = l_run[qt] * sc[qt] + acc;
    }

    // ---- PV: barrier-free; wave w owns d-cols [48w, 48w+48) ----
#pragma unroll
    for (int ksv = 0; ksv < 4; ++ksv) {
      short8 pf0 = *reinterpret_cast<const short8*>(
          LDSU + OFF_P + (l15)*136 + 32 * ksv + 8 * hi4);
      short8 pf1 = *reinterpret_cast<const short8*>(
          LDSU + OFF_P + (16 + l15) * 136 + 32 * ksv + 8 * hi4);
      short8 pf2 = *reinterpret_cast<const short8*>(
          LDSU + OFF_P + (32 + l15) * 136 + 32 * ksv + 8 * hi4);
      short8 pf3 = *reinterpret_cast<const short8*>(
          LDSU + OFF_P + (48 + l15) * 136 + 32 * ksv + 8 * hi4);
#pragma unroll
      for (int c = 0; c < 3; ++c) {
        const size_t g =
            (size_t)(48 * w + 16 * c + l15) * kN + kg + 32 * ksv + 8 * hi4;
        const short8 vfh = *reinterpret_cast<const short8*>(VTh + g);
        const short8 vfl = *reinterpret_cast<const short8*>(VTl + g);
        o[0][c] = mfma_bf16(pf0, vfh, o[0][c]);
        o[0][c] = mfma_bf16(pf0, vfl, o[0][c]);
        o[1][c] = mfma_bf16(pf1, vfh, o[1][c]);
        o[1][c] = mfma_bf16(pf1, vfl, o[1][c]);
        o[2][c] = mfma_bf16(pf2, vfh, o[2][c]);
        o[2][c] = mfma_bf16(pf2, vfl, o[2][c]);
        o[3][c] = mfma_bf16(pf3, vfh, o[3][c]);
        o[3][c] = mfma_bf16(pf3, vfl, o[3][c]);
      }
    }
  }

  // ---- write NORMALIZED partials (nontemporal) + (m,l) ----
#pragma unroll
  for (int qt = 0; qt < 4; ++qt) {
    const float linv = 1.0f / l_run[qt];
#pragma unroll
    for (int r = 0; r < 4; ++r) {
      const float lr = __shfl(linv, 4 * hi4 + r, 64);
#pragma unroll
      for (int c = 0; c < 3; ++c)
        storeO(&Opart[(size_t)sp * kND + (i0 + 16 * qt + 4 * hi4 + r) * kD +
                      48 * w + 16 * c + l15],
               o[qt][c][r] * lr);
    }
  }
  if (w == 0 && lane < 16) {
#pragma unroll
    for (int qt = 0; qt < 4; ++qt) {
      const int mi = (sp * kN + i0 + 16 * qt + l15) * 2;
      ml[mi] = m_run[qt];
      ml[mi + 1] = l_run[qt];
    }
  }
}

// ---------------------------------------------------------------------------
// Merge NSPLIT normalized partials:
// h1 = sum_sp w_sp * On_sp,  w_sp = e^{m_sp-m} l_sp / sum e^{m_sp-m} l_sp
// ---------------------------------------------------------------------------
template <int NSPLIT, typename OT>
__global__ __launch_bounds__(256) void merge_kernel(
    const OT* __restrict__ Opart, const float* __restrict__ ml,
    float* __restrict__ O)
{
  const size_t idx = (size_t)blockIdx.x * 256 + threadIdx.x;
  const size_t i = idx / kD;
  float m = ml[i * 2];
#pragma unroll
  for (int sp = 1; sp < NSPLIT; ++sp)
    m = fmaxf(m, ml[((size_t)sp * kN + i) * 2]);
  float wsum = 0.f, acc = 0.f;
#pragma unroll
  for (int sp = 0; sp < NSPLIT; ++sp) {
    const float e = __expf(ml[((size_t)sp * kN + i) * 2] - m) *
                    ml[((size_t)sp * kN + i) * 2 + 1];
    wsum += e;
    acc += e * loadO(&Opart[(size_t)sp * kND + idx]);
  }
  O[idx] = acc / wsum;
}

// ---------------------------------------------------------------------------
// Layer-2 helpers (only last row of layer 2 needed)
// ---------------------------------------------------------------------------
__global__ __launch_bounds__(64) void qrow_kernel(
    const float* __restrict__ h1, const float* __restrict__ Wq,
    float* __restrict__ q2)
{
  const int j = blockIdx.x;
  const int lane = threadIdx.x;
  const float* hr = h1 + (size_t)(kN - 1) * kD;
  float acc = 0.f;
  for (int d = lane; d < kD; d += 64) acc += hr[d] * Wq[(size_t)j * kD + d];
#pragma unroll
  for (int off = 32; off > 0; off >>= 1) acc += __shfl_xor(acc, off, 64);
  if (lane == 0) q2[j] = acc;
}

__global__ __launch_bounds__(256) void logits_kernel(
    const float* __restrict__ Kt2, const float* __restrict__ q2,
    float* __restrict__ lg)
{
  const int wave = threadIdx.x >> 6;
  const int lane = threadIdx.x & 63;
  const int j = blockIdx.x * 4 + wave;
  float acc = 0.f;
#pragma unroll
  for (int t = 0; t < kD / 64; ++t) {
    const int d = lane + t * 64;
    acc += Kt2[(size_t)j * kD + d] * q2[d];
  }
#pragma unroll
  for (int off = 32; off > 0; off >>= 1) acc += __shfl_xor(acc, off, 64);
  if (lane == 0) lg[j] = acc;
}

__global__ __launch_bounds__(1024) void smax_kernel(
    const float* __restrict__ lg, float* __restrict__ wgt)
{
  __shared__ float red[16];
  const int t = threadIdx.x;
  const int wave = t >> 6;
  const int lane = t & 63;
  float v[8];
  float mx = -INFINITY;
#pragma unroll
  for (int s = 0; s < 8; ++s) {
    v[s] = lg[t + 1024 * s];
    mx = fmaxf(mx, v[s]);
  }
#pragma unroll
  for (int off = 32; off > 0; off >>= 1) mx = fmaxf(mx, __shfl_xor(mx, off, 64));
  if (lane == 0) red[wave] = mx;
  __syncthreads();
  if (t == 0) {
    float m = red[0];
    for (int i = 1; i < 16; ++i) m = fmaxf(m, red[i]);
    red[0] = m;
  }
  __syncthreads();
  const float m = red[0];
  __syncthreads();
  float sum = 0.f;
#pragma unroll
  for (int s = 0; s < 8; ++s) {
    v[s] = expf(v[s] - m);
    sum += v[s];
  }
#pragma unroll
  for (int off = 32; off > 0; off >>= 1) sum += __shfl_xor(sum, off, 64);
  if (lane == 0) red[wave] = sum;
  __syncthreads();
  if (t == 0) {
    float S = 0.f;
    for (int i = 0; i < 16; ++i) S += red[i];
    red[0] = S;
  }
  __syncthreads();
  const float invS = 1.0f / red[0];
#pragma unroll
  for (int s = 0; s < 8; ++s) wgt[t + 1024 * s] = v[s] * invS;
}

__global__ __launch_bounds__(384) void wsum_kernel(
    const float* __restrict__ wgt, const float* __restrict__ Vt2,
    float* __restrict__ part)
{
  __shared__ float wl[256];
  const int b = blockIdx.x;
  const int t = threadIdx.x;
  if (t < 256) wl[t] = wgt[b * 256 + t];
  __syncthreads();
  const float* Vp = Vt2 + (size_t)b * 256 * kD;
  float acc = 0.f;
  for (int j = 0; j < 256; ++j) acc += wl[j] * Vp[(size_t)j * kD + t];
  part[b * kD + t] = acc;
}

__global__ __launch_bounds__(384) void final_kernel(
    const float* __restrict__ part, const float* __restrict__ ffws,
    float* __restrict__ out)
{
  __shared__ float red[6];
  const int t = threadIdx.x;
  const int wave = t >> 6;
  const int lane = t & 63;
  float z = 0.f;
#pragma unroll
  for (int b = 0; b < 32; ++b) z += part[b * kD + t];
  float val = z * ffws[t];
#pragma unroll
  for (int off = 32; off > 0; off >>= 1) val += __shfl_xor(val, off, 64);
  if (lane == 0) red[wave] = val;
  __syncthreads();
  if (t == 0) {
    float s = red[0];
    for (int i = 1; i < 6; ++i) s += red[i];
    out[0] = 1.0f / (1.0f + expf(-s));
  }
}

// ---------------------------------------------------------------------------
extern "C" void kernel_launch(void* const* d_in, const int* in_sizes, int n_in,
                              void* d_out, int out_size, void* d_ws, size_t ws_size,
                              hipStream_t stream) {
  const float* x    = (const float*)d_in[0];
  const float* Wq   = (const float*)d_in[1];
  const float* Wk   = (const float*)d_in[2];
  const float* Wv   = (const float*)d_in[3];
  const float* ffws = (const float*)d_in[4];
  float* out = (float*)d_out;
  char* wsb = (char*)d_ws;

  ushort* Qh  = (ushort*)wsb;
  ushort* Ql  = Qh + kND;
  ushort* Kh  = Ql + kND;
  ushort* Kl  = Kh + kND;
  ushort* VTh = Kl + kND;
  ushort* VTl = VTh + kND;
  const size_t bfQKV = 6 * (size_t)kND * 2;           // 37,748,736

  // variant workspace needs
  const size_t opA = 8 * (size_t)kND * 4, mlAB = 8 * (size_t)kN * 2 * 4;
  const size_t opB = 8 * (size_t)kND * 2;
  const size_t opC = 2 * (size_t)kND * 4, mlC = 2 * (size_t)kN * 2 * 4;
  const size_t h1B = (size_t)kND * 4;
  const size_t smallB = kD * 4 + kN * 4 + kN * 4 + 32 * kD * 4;
  const size_t needA = bfQKV + opA + mlAB + h1B + smallB;  // ~151.6 MB
  const size_t needB = bfQKV + opB + mlAB + h1B + smallB;  // ~101.3 MB

  // phase-2 overlays (dead bf16 regions) + smalls over Opart (dead post-merge)
  float* Kt2 = (float*)wsb;                          // over Qh/Ql
  float* Vt2 = (float*)(wsb + 2 * (size_t)kND * 2);  // over Kh/Kl
  float* q2  = (float*)(wsb + bfQKV);                // over Opart
  float* lg  = q2 + kD;
  float* wgt = lg + kN;
  float* part = wgt + kN;

  const dim3 gg(kN / 64, kD / 64);
  gemm_xwT<1><<<gg, 256, 0, stream>>>(x, Wq, nullptr, Qh, Ql);
  gemm_xwT<1><<<gg, 256, 0, stream>>>(x, Wk, nullptr, Kh, Kl);
  gemm_xwT<2><<<gg, 256, 0, stream>>>(x, Wv, nullptr, VTh, VTl);

  float* h1;
  if (ws_size >= needA) {
    float* Op = (float*)(wsb + bfQKV);
    float* ml = (float*)(wsb + bfQKV + opA);
    h1 = (float*)(wsb + bfQKV + opA + mlAB);
    flash_mfma<8, float><<<(kN / 64) * 8, 512, 0, stream>>>(
        Qh, Ql, Kh, Kl, VTh, VTl, Op, ml);
    merge_kernel<8, float><<<(kN * kD) / 256, 256, 0, stream>>>(Op, ml, h1);
  } else if (ws_size >= needB) {
    ushort* Op = (ushort*)(wsb + bfQKV);
    float* ml = (float*)(wsb + bfQKV + opB);
    h1 = (float*)(wsb + bfQKV + opB + mlAB);
    flash_mfma<8, ushort><<<(kN / 64) * 8, 512, 0, stream>>>(
        Qh, Ql, Kh, Kl, VTh, VTl, Op, ml);
    merge_kernel<8, ushort><<<(kN * kD) / 256, 256, 0, stream>>>(Op, ml, h1);
  } else {
    // r4-proven fallback: SPLIT=2, fp32, h1 overlays VT region
    float* Op = (float*)(wsb + bfQKV);
    float* ml = (float*)(wsb + bfQKV + opC);
    h1 = (float*)(wsb + 4 * (size_t)kND * 2);
    flash_mfma<2, float><<<(kN / 64) * 2, 512, 0, stream>>>(
        Qh, Ql, Kh, Kl, VTh, VTl, Op, ml);
    merge_kernel<2, float><<<(kN * kD) / 256, 256, 0, stream>>>(Op, ml, h1);
  }

  gemm_xwT<0><<<gg, 256, 0, stream>>>(h1, Wk, Kt2, nullptr, nullptr);
  gemm_xwT<0><<<gg, 256, 0, stream>>>(h1, Wv, Vt2, nullptr, nullptr);
  qrow_kernel<<<kD, 64, 0, stream>>>(h1, Wq, q2);
  logits_kernel<<<kN / 4, 256, 0, stream>>>(Kt2, q2, lg);
  smax_kernel<<<1, 1024, 0, stream>>>(lg, wgt);
  wsum_kernel<<<32, 384, 0, stream>>>(wgt, Vt2, part);
  final_kernel<<<1, 384, 0, stream>>>(part, ffws, out);
}

// Round 7
// 608.981 us; speedup vs baseline: 1.4680x; 1.1028x over previous
//
#include <hip/hip_runtime.h>
#include <hip/hip_bf16.h>
#include <math.h>

static constexpr int kN = 8192;
static constexpr int kD = 384;
static constexpr int kND = kN * kD;

typedef __attribute__((ext_vector_type(8))) short short8;
typedef __attribute__((ext_vector_type(4))) float f32x4;

// ---- bf16 helpers (bit-exact RNE) ----
__device__ __forceinline__ ushort f2bf(float f) {
  union { float f; unsigned int i; } cv; cv.f = f;
  unsigned int lsb = (cv.i >> 16) & 1u;
  unsigned int r = cv.i + 0x7fffu + lsb;
  return (ushort)(r >> 16);
}
__device__ __forceinline__ float bf2f(ushort u) {
  union { unsigned int i; float f; } cv; cv.i = ((unsigned int)u) << 16;
  return cv.f;
}
__device__ __forceinline__ f32x4 mfma_bf16(short8 a, short8 b, f32x4 c) {
  return __builtin_amdgcn_mfma_f32_16x16x32_bf16(a, b, c, 0, 0, 0);
}
// 3-term compensated product: ah*bh + ah*bl + al*bh  (error ~2^-16)
__device__ __forceinline__ f32x4 mfma3(short8 ah, short8 al, short8 bh, short8 bl, f32x4 c) {
  c = mfma_bf16(ah, bh, c);
  c = mfma_bf16(ah, bl, c);
  c = mfma_bf16(al, bh, c);
  return c;
}
// LDS-only barrier: drains ds ops for cross-wave visibility but lets
// in-flight GLOBAL loads (register prefetch) survive the barrier.
__device__ __forceinline__ void bar_lds() {
  asm volatile("s_waitcnt lgkmcnt(0)" ::: "memory");
  __builtin_amdgcn_s_barrier();
}

// ---------------------------------------------------------------------------
// GEMM: Y = X[kN][kD] @ W[kD][kD]^T.
// MODE 0: fp32 out. MODE 1: bf16 hi/lo out. MODE 2: bf16 hi/lo transposed.
// ---------------------------------------------------------------------------
template <int MODE>
__global__ __launch_bounds__(256) void gemm_xwT(
    const float* __restrict__ X, const float* __restrict__ W,
    float* __restrict__ Y, ushort* __restrict__ Yh, ushort* __restrict__ Yl)
{
  __shared__ float Xs[64][33];
  __shared__ float WsT[32][68];
  const int tid = threadIdx.x;
  const int tx = tid & 15;
  const int ty = tid >> 4;
  const int i0 = blockIdx.x * 64;
  const int j0 = blockIdx.y * 64;
  float acc[4][4] = {};

  for (int k0 = 0; k0 < kD; k0 += 32) {
#pragma unroll
    for (int s = 0; s < 2; ++s) {
      const int f = tid + 256 * s;
      const int row = f >> 3;
      const int c4 = (f & 7) * 4;
      const float4 v = *reinterpret_cast<const float4*>(
          &X[(size_t)(i0 + row) * kD + k0 + c4]);
      Xs[row][c4 + 0] = v.x; Xs[row][c4 + 1] = v.y;
      Xs[row][c4 + 2] = v.z; Xs[row][c4 + 3] = v.w;
    }
#pragma unroll
    for (int s = 0; s < 2; ++s) {
      const int f = tid + 256 * s;
      const int col = f >> 3;
      const int c4 = (f & 7) * 4;
      const float4 v = *reinterpret_cast<const float4*>(
          &W[(size_t)(j0 + col) * kD + k0 + c4]);
      WsT[c4 + 0][col] = v.x; WsT[c4 + 1][col] = v.y;
      WsT[c4 + 2][col] = v.z; WsT[c4 + 3][col] = v.w;
    }
    __syncthreads();
#pragma unroll
    for (int kk = 0; kk < 32; ++kk) {
      const float4 b = *reinterpret_cast<const float4*>(&WsT[kk][tx * 4]);
      const float a0 = Xs[ty * 4 + 0][kk];
      const float a1 = Xs[ty * 4 + 1][kk];
      const float a2 = Xs[ty * 4 + 2][kk];
      const float a3 = Xs[ty * 4 + 3][kk];
      acc[0][0] += a0 * b.x; acc[0][1] += a0 * b.y; acc[0][2] += a0 * b.z; acc[0][3] += a0 * b.w;
      acc[1][0] += a1 * b.x; acc[1][1] += a1 * b.y; acc[1][2] += a1 * b.z; acc[1][3] += a1 * b.w;
      acc[2][0] += a2 * b.x; acc[2][1] += a2 * b.y; acc[2][2] += a2 * b.z; acc[2][3] += a2 * b.w;
      acc[3][0] += a3 * b.x; acc[3][1] += a3 * b.y; acc[3][2] += a3 * b.z; acc[3][3] += a3 * b.w;
    }
    __syncthreads();
  }
  if constexpr (MODE == 0) {
#pragma unroll
    for (int r = 0; r < 4; ++r) {
      float4 v;
      v.x = acc[r][0]; v.y = acc[r][1]; v.z = acc[r][2]; v.w = acc[r][3];
      *reinterpret_cast<float4*>(
          &Y[(size_t)(i0 + ty * 4 + r) * kD + j0 + tx * 4]) = v;
    }
  } else if constexpr (MODE == 1) {
#pragma unroll
    for (int r = 0; r < 4; ++r) {
      ushort4 h, l;
      ushort* hp = &h.x; ushort* lp = &l.x;
#pragma unroll
      for (int c = 0; c < 4; ++c) {
        const float f = acc[r][c];
        const ushort hh = f2bf(f);
        hp[c] = hh;
        lp[c] = f2bf(f - bf2f(hh));
      }
      const int oi = (i0 + ty * 4 + r) * kD + j0 + tx * 4;
      *reinterpret_cast<ushort4*>(&Yh[oi]) = h;
      *reinterpret_cast<ushort4*>(&Yl[oi]) = l;
    }
  } else {
#pragma unroll
    for (int c = 0; c < 4; ++c) {
      ushort4 h, l;
      ushort* hp = &h.x; ushort* lp = &l.x;
#pragma unroll
      for (int r = 0; r < 4; ++r) {
        const float f = acc[r][c];
        const ushort hh = f2bf(f);
        hp[r] = hh;
        lp[r] = f2bf(f - bf2f(hh));
      }
      const int oi = (j0 + tx * 4 + c) * kN + i0 + ty * 4;
      *reinterpret_cast<ushort4*>(&Yh[oi]) = h;
      *reinterpret_cast<ushort4*>(&Yl[oi]) = l;
    }
  }
}

// ---------------------------------------------------------------------------
// MFMA flash attention v7: r4 structure + explicit register prefetch across
// raw (LDS-only) barriers.  BM=64, 512 threads (8 waves), SPLIT=2.
// Per tile: V-frags for THIS tile issued into regs before S-phase (latency
// hidden under 144 S-MFMAs); K-frags for NEXT tile issued before PV (hidden
// under 48 PV-MFMAs + softmax).  PV is 1-term (P*Vh) — V-lo dropped.
// LDS: Qh 49K | Ql 49K | P 17.4K | MLB 4K -> 1 block/CU, 8 waves.
// ---------------------------------------------------------------------------
static constexpr int SPLITf = 2;
static constexpr int KEYSf = kN / SPLITf;   // 4096
static constexpr int NTIL = KEYSf / 128;    // 32

static constexpr int OFF_QH = 0;       // ushort offsets into LDSU
static constexpr int OFF_QL = 25088;   // 64*392
static constexpr int OFF_P  = 50176;

__global__ __launch_bounds__(512, 2) void flash_mfma(
    const ushort* __restrict__ Qh, const ushort* __restrict__ Ql,
    const ushort* __restrict__ Kh, const ushort* __restrict__ Kl,
    const ushort* __restrict__ VTh,
    float* __restrict__ Opart, float* __restrict__ ml)
{
  __shared__ ushort LDSU[58880];   // 117760 B
  __shared__ float MLB[1024];      // m: [0,512), l: [512,1024)

  const int tid = threadIdx.x;
  const int w = tid >> 6;
  const int lane = tid & 63;
  const int l15 = lane & 15;
  const int hi4 = lane >> 4;
  const int sp = blockIdx.x;
  const int i0 = blockIdx.y * 64;
  const int kg0 = sp * KEYSf;

  // ---- stage Q-hi + Q-lo once ----
  {
    const int row = tid >> 3;
    const int sg = (tid & 7) * 48;
    const ushort* sh = Qh + (size_t)(i0 + row) * kD + sg;
    const ushort* sl = Ql + (size_t)(i0 + row) * kD + sg;
    ushort* dh = LDSU + OFF_QH + row * 392 + sg;
    ushort* dl = LDSU + OFF_QL + row * 392 + sg;
#pragma unroll
    for (int u = 0; u < 6; ++u) {
      *reinterpret_cast<uint4*>(dh + 8 * u) =
          *reinterpret_cast<const uint4*>(sh + 8 * u);
      *reinterpret_cast<uint4*>(dl + 8 * u) =
          *reinterpret_cast<const uint4*>(sl + 8 * u);
    }
  }

  const f32x4 zf = {0.f, 0.f, 0.f, 0.f};
  f32x4 o[4][3];
#pragma unroll
  for (int qt = 0; qt < 4; ++qt)
#pragma unroll
    for (int c = 0; c < 3; ++c) o[qt][c] = zf;
  float m_run[4], l_run[4];
#pragma unroll
  for (int qt = 0; qt < 4; ++qt) { m_run[qt] = -INFINITY; l_run[qt] = 0.f; }

  // ---- initial K prefetch (tile 0) ----
  short8 krh[12], krl[12];
  {
    const size_t kb0 = (size_t)(kg0 + 16 * w + l15) * kD + 8 * hi4;
#pragma unroll
    for (int ks = 0; ks < 12; ++ks) {
      krh[ks] = *reinterpret_cast<const short8*>(Kh + kb0 + 32 * ks);
      krl[ks] = *reinterpret_cast<const short8*>(Kl + kb0 + 32 * ks);
    }
  }

  __syncthreads();   // Q staged (full barrier once)

  for (int kb = 0; kb < NTIL; ++kb) {
    const int kg = kg0 + kb * 128;

    // ---- issue V-frag loads for THIS tile (consumed in PV) ----
    short8 vr[3][4];
#pragma unroll
    for (int c = 0; c < 3; ++c)
#pragma unroll
      for (int kv = 0; kv < 4; ++kv)
        vr[c][kv] = *reinterpret_cast<const short8*>(
            VTh + (size_t)(48 * w + 16 * c + l15) * kN + kg + 32 * kv + 8 * hi4);

    // ---- S phase: K from regs (prefetched), Q hi/lo from LDS ----
    f32x4 sacc[4];
#pragma unroll
    for (int qt = 0; qt < 4; ++qt) sacc[qt] = zf;
#pragma unroll
    for (int ks = 0; ks < 12; ++ks) {
      const int d0 = 32 * ks;
#pragma unroll
      for (int qt = 0; qt < 4; ++qt) {
        const int qoff = (16 * qt + l15) * 392 + d0 + 8 * hi4;
        const short8 qh = *reinterpret_cast<const short8*>(LDSU + OFF_QH + qoff);
        const short8 ql = *reinterpret_cast<const short8*>(LDSU + OFF_QL + qoff);
        sacc[qt] = mfma3(krh[ks], krl[ks], qh, ql, sacc[qt]);
      }
    }

    // ---- online softmax ----
    float mt4[4];
#pragma unroll
    for (int qt = 0; qt < 4; ++qt) {
      float mt = fmaxf(fmaxf(sacc[qt][0], sacc[qt][1]),
                       fmaxf(sacc[qt][2], sacc[qt][3]));
      mt = fmaxf(mt, __shfl_xor(mt, 16, 64));
      mt = fmaxf(mt, __shfl_xor(mt, 32, 64));
      mt4[qt] = mt;
    }
    if (lane < 16) {
#pragma unroll
      for (int qt = 0; qt < 4; ++qt) MLB[w * 64 + qt * 16 + l15] = mt4[qt];
    }
    bar_lds();  // B1
    float sc[4];
#pragma unroll
    for (int qt = 0; qt < 4; ++qt) {
      float Mt = MLB[qt * 16 + l15];
#pragma unroll
      for (int w2 = 1; w2 < 8; ++w2)
        Mt = fmaxf(Mt, MLB[w2 * 64 + qt * 16 + l15]);
      const float mnew = fmaxf(m_run[qt], Mt);
      sc[qt] = __expf(m_run[qt] - mnew);
      m_run[qt] = mnew;
      const float p0 = __expf(sacc[qt][0] - mnew);
      const float p1 = __expf(sacc[qt][1] - mnew);
      const float p2 = __expf(sacc[qt][2] - mnew);
      const float p3 = __expf(sacc[qt][3] - mnew);
      float ls = (p0 + p1) + (p2 + p3);
      ls += __shfl_xor(ls, 16, 64);
      ls += __shfl_xor(ls, 32, 64);
      if (lane < 16) MLB[512 + w * 64 + qt * 16 + l15] = ls;
      // pack P -> bf16 hi only, one b64 write
      uint2 HH;
      HH.x = (unsigned int)f2bf(p0) | ((unsigned int)f2bf(p1) << 16);
      HH.y = (unsigned int)f2bf(p2) | ((unsigned int)f2bf(p3) << 16);
      const int pi = (16 * qt + l15) * 136 + 16 * w + 4 * hi4;
      *reinterpret_cast<uint2*>(LDSU + OFF_P + pi) = HH;
      // rescale O (row of o = qrow 16qt+4*hi4+r)
#pragma unroll
      for (int r = 0; r < 4; ++r) {
        const float scr_ = __shfl(sc[qt], 4 * hi4 + r, 64);
#pragma unroll
        for (int c = 0; c < 3; ++c) o[qt][c][r] *= scr_;
      }
    }
    bar_lds();  // B2: P + mlb_l ready
#pragma unroll
    for (int qt = 0; qt < 4; ++qt) {
      float acc = MLB[512 + qt * 16 + l15];
#pragma unroll
      for (int w2 = 1; w2 < 8; ++w2) acc += MLB[512 + w2 * 64 + qt * 16 + l15];
      l_run[qt] = l_run[qt] * sc[qt] + acc;
    }

    // ---- prefetch K for NEXT tile (hidden under PV + next softmax) ----
    if (kb + 1 < NTIL) {
      const size_t kbn = (size_t)(kg + 128 + 16 * w + l15) * kD + 8 * hi4;
#pragma unroll
      for (int ks = 0; ks < 12; ++ks) {
        krh[ks] = *reinterpret_cast<const short8*>(Kh + kbn + 32 * ks);
        krl[ks] = *reinterpret_cast<const short8*>(Kl + kbn + 32 * ks);
      }
    }

    // ---- PV: barrier-free; wave w owns d-cols [48w,48w+48); V from regs ----
#pragma unroll
    for (int kv = 0; kv < 4; ++kv) {
      short8 pf0 = *reinterpret_cast<const short8*>(
          LDSU + OFF_P + (l15)*136 + 32 * kv + 8 * hi4);
      short8 pf1 = *reinterpret_cast<const short8*>(
          LDSU + OFF_P + (16 + l15) * 136 + 32 * kv + 8 * hi4);
      short8 pf2 = *reinterpret_cast<const short8*>(
          LDSU + OFF_P + (32 + l15) * 136 + 32 * kv + 8 * hi4);
      short8 pf3 = *reinterpret_cast<const short8*>(
          LDSU + OFF_P + (48 + l15) * 136 + 32 * kv + 8 * hi4);
#pragma unroll
      for (int c = 0; c < 3; ++c) {
        o[0][c] = mfma_bf16(pf0, vr[c][kv], o[0][c]);
        o[1][c] = mfma_bf16(pf1, vr[c][kv], o[1][c]);
        o[2][c] = mfma_bf16(pf2, vr[c][kv], o[2][c]);
        o[3][c] = mfma_bf16(pf3, vr[c][kv], o[3][c]);
      }
    }
  }

  // ---- write unnormalized partials + (m,l); waves own disjoint d-cols ----
#pragma unroll
  for (int qt = 0; qt < 4; ++qt)
#pragma unroll
    for (int c = 0; c < 3; ++c)
#pragma unroll
      for (int r = 0; r < 4; ++r)
        Opart[(size_t)sp * kND + (i0 + 16 * qt + 4 * hi4 + r) * kD +
              48 * w + 16 * c + l15] = o[qt][c][r];
  if (w == 0 && lane < 16) {
#pragma unroll
    for (int qt = 0; qt < 4; ++qt) {
      const int mi = (sp * kN + i0 + 16 * qt + l15) * 2;
      ml[mi] = m_run[qt];
      ml[mi + 1] = l_run[qt];
    }
  }
}

// ---------------------------------------------------------------------------
// Merge 2 key-split partials
// ---------------------------------------------------------------------------
__global__ __launch_bounds__(256) void merge_kernel(
    const float* __restrict__ Opart, const float* __restrict__ ml,
    float* __restrict__ O)
{
  const size_t idx = (size_t)blockIdx.x * 256 + threadIdx.x;
  const size_t i = idx / kD;
  const float m0 = ml[i * 2];
  const float l0 = ml[i * 2 + 1];
  const float m1 = ml[((size_t)kN + i) * 2];
  const float l1 = ml[((size_t)kN + i) * 2 + 1];
  const float m = fmaxf(m0, m1);
  const float e0 = expf(m0 - m);
  const float e1 = expf(m1 - m);
  const float inv = 1.0f / (e0 * l0 + e1 * l1);
  O[idx] = (e0 * Opart[idx] + e1 * Opart[(size_t)kND + idx]) * inv;
}

// ---------------------------------------------------------------------------
// Layer-2: exact matvec formulation (no full GEMMs needed).
//   q2 = Wq . h1[-1]        (qrow_kernel)
//   u  = Wk^T . q2          (u_kernel)
//   lg = h1 . u             (logits_kernel)
//   wgt = softmax(lg)       (smax_kernel)
//   z  = h1^T . wgt         (wsum_kernel partials -> final2)
//   out = sigmoid(sum(ffws * (Wv . z)))   (final2_kernel)
// ---------------------------------------------------------------------------
__global__ __launch_bounds__(64) void qrow_kernel(
    const float* __restrict__ h1, const float* __restrict__ Wq,
    float* __restrict__ q2)
{
  const int j = blockIdx.x;
  const int lane = threadIdx.x;
  const float* hr = h1 + (size_t)(kN - 1) * kD;
  float acc = 0.f;
  for (int d = lane; d < kD; d += 64) acc += hr[d] * Wq[(size_t)j * kD + d];
#pragma unroll
  for (int off = 32; off > 0; off >>= 1) acc += __shfl_xor(acc, off, 64);
  if (lane == 0) q2[j] = acc;
}

__global__ __launch_bounds__(384) void u_kernel(
    const float* __restrict__ Wk, const float* __restrict__ q2,
    float* __restrict__ u)
{
  __shared__ float qs[kD];
  const int d = threadIdx.x;
  qs[d] = q2[d];
  __syncthreads();
  float acc = 0.f;
  for (int k = 0; k < kD; ++k) acc += Wk[(size_t)k * kD + d] * qs[k];
  u[d] = acc;
}

__global__ __launch_bounds__(256) void logits_kernel(
    const float* __restrict__ h1, const float* __restrict__ u,
    float* __restrict__ lg)
{
  const int wave = threadIdx.x >> 6;
  const int lane = threadIdx.x & 63;
  const int j = blockIdx.x * 4 + wave;
  float acc = 0.f;
#pragma unroll
  for (int t = 0; t < kD / 64; ++t) {
    const int d = lane + t * 64;
    acc += h1[(size_t)j * kD + d] * u[d];
  }
#pragma unroll
  for (int off = 32; off > 0; off >>= 1) acc += __shfl_xor(acc, off, 64);
  if (lane == 0) lg[j] = acc;
}

__global__ __launch_bounds__(1024) void smax_kernel(
    const float* __restrict__ lg, float* __restrict__ wgt)
{
  __shared__ float red[16];
  const int t = threadIdx.x;
  const int wave = t >> 6;
  const int lane = t & 63;
  float v[8];
  float mx = -INFINITY;
#pragma unroll
  for (int s = 0; s < 8; ++s) {
    v[s] = lg[t + 1024 * s];
    mx = fmaxf(mx, v[s]);
  }
#pragma unroll
  for (int off = 32; off > 0; off >>= 1) mx = fmaxf(mx, __shfl_xor(mx, off, 64));
  if (lane == 0) red[wave] = mx;
  __syncthreads();
  if (t == 0) {
    float m = red[0];
    for (int i = 1; i < 16; ++i) m = fmaxf(m, red[i]);
    red[0] = m;
  }
  __syncthreads();
  const float m = red[0];
  __syncthreads();
  float sum = 0.f;
#pragma unroll
  for (int s = 0; s < 8; ++s) {
    v[s] = expf(v[s] - m);
    sum += v[s];
  }
#pragma unroll
  for (int off = 32; off > 0; off >>= 1) sum += __shfl_xor(sum, off, 64);
  if (lane == 0) red[wave] = sum;
  __syncthreads();
  if (t == 0) {
    float S = 0.f;
    for (int i = 0; i < 16; ++i) S += red[i];
    red[0] = S;
  }
  __syncthreads();
  const float invS = 1.0f / red[0];
#pragma unroll
  for (int s = 0; s < 8; ++s) wgt[t + 1024 * s] = v[s] * invS;
}

// part[b][d] = sum_{j in block b's 256 rows} wgt[j] * h1[j][d]
__global__ __launch_bounds__(384) void wsum_kernel(
    const float* __restrict__ wgt, const float* __restrict__ h1,
    float* __restrict__ part)
{
  __shared__ float wl[256];
  const int b = blockIdx.x;
  const int t = threadIdx.x;
  if (t < 256) wl[t] = wgt[b * 256 + t];
  __syncthreads();
  const float* Hp = h1 + (size_t)b * 256 * kD;
  float acc = 0.f;
  for (int j = 0; j < 256; ++j) acc += wl[j] * Hp[(size_t)j * kD + t];
  part[b * kD + t] = acc;
}

__global__ __launch_bounds__(384) void final2_kernel(
    const float* __restrict__ part, const float* __restrict__ Wv,
    const float* __restrict__ ffws, float* __restrict__ out)
{
  __shared__ float zs[kD];
  __shared__ float red[6];
  const int t = threadIdx.x;
  const int wave = t >> 6;
  const int lane = t & 63;
  float z = 0.f;
#pragma unroll
  for (int b = 0; b < 32; ++b) z += part[b * kD + t];
  zs[t] = z;
  __syncthreads();
  float zv = 0.f;
  for (int k = 0; k < kD; ++k) zv += Wv[(size_t)t * kD + k] * zs[k];
  float val = zv * ffws[t];
#pragma unroll
  for (int off = 32; off > 0; off >>= 1) val += __shfl_xor(val, off, 64);
  if (lane == 0) red[wave] = val;
  __syncthreads();
  if (t == 0) {
    float s = red[0];
    for (int i = 1; i < 6; ++i) s += red[i];
    out[0] = 1.0f / (1.0f + expf(-s));
  }
}

// ---------------------------------------------------------------------------
extern "C" void kernel_launch(void* const* d_in, const int* in_sizes, int n_in,
                              void* d_out, int out_size, void* d_ws, size_t ws_size,
                              hipStream_t stream) {
  const float* x    = (const float*)d_in[0];
  const float* Wq   = (const float*)d_in[1];
  const float* Wk   = (const float*)d_in[2];
  const float* Wv   = (const float*)d_in[3];
  const float* ffws = (const float*)d_in[4];
  float* out = (float*)d_out;
  char* wsb = (char*)d_ws;

  ushort* Qh  = (ushort*)wsb;
  ushort* Ql  = Qh + kND;
  ushort* Kh  = Ql + kND;
  ushort* Kl  = Kh + kND;
  ushort* VTh = Kl + kND;
  ushort* VTl = VTh + kND;                 // written by MODE 2, unused by flash
  const size_t bfQKV = 6 * (size_t)kND * 2;
  float* Opart = (float*)(wsb + bfQKV);
  float* ml    = Opart + 2 * (size_t)kND;
  float* h1    = ml + 4 * (size_t)kN;
  float* q2    = h1 + (size_t)kND;
  float* u     = q2 + kD;
  float* lg    = u + kD;
  float* wgt   = lg + kN;
  float* part  = wgt + kN;

  const dim3 gg(kN / 64, kD / 64);
  // layer-1 projections -> bf16 hi/lo operands
  gemm_xwT<1><<<gg, 256, 0, stream>>>(x, Wq, nullptr, Qh, Ql);
  gemm_xwT<1><<<gg, 256, 0, stream>>>(x, Wk, nullptr, Kh, Kl);
  gemm_xwT<2><<<gg, 256, 0, stream>>>(x, Wv, nullptr, VTh, VTl);
  // layer-1 attention
  flash_mfma<<<dim3(SPLITf, kN / 64), 512, 0, stream>>>(
      Qh, Ql, Kh, Kl, VTh, Opart, ml);
  merge_kernel<<<(kN * kD) / 256, 256, 0, stream>>>(Opart, ml, h1);
  // layer-2 (exact matvec chain)
  qrow_kernel<<<kD, 64, 0, stream>>>(h1, Wq, q2);
  u_kernel<<<1, 384, 0, stream>>>(Wk, q2, u);
  logits_kernel<<<kN / 4, 256, 0, stream>>>(h1, u, lg);
  smax_kernel<<<1, 1024, 0, stream>>>(lg, wgt);
  wsum_kernel<<<32, 384, 0, stream>>>(wgt, h1, part);
  final2_kernel<<<1, 384, 0, stream>>>(part, Wv, ffws, out);
}

// Round 8
// 497.781 us; speedup vs baseline: 1.7959x; 1.2234x over previous
//
#include <hip/hip_runtime.h>
#include <hip/hip_bf16.h>
#include <math.h>

static constexpr int kN = 8192;
static constexpr int kD = 384;
static constexpr int kND = kN * kD;

typedef __attribute__((ext_vector_type(8))) short short8;
typedef __attribute__((ext_vector_type(4))) float f32x4;

// ---- bf16 helpers (bit-exact RNE) ----
__device__ __forceinline__ ushort f2bf(float f) {
  union { float f; unsigned int i; } cv; cv.f = f;
  unsigned int lsb = (cv.i >> 16) & 1u;
  unsigned int r = cv.i + 0x7fffu + lsb;
  return (ushort)(r >> 16);
}
__device__ __forceinline__ float bf2f(ushort u) {
  union { unsigned int i; float f; } cv; cv.i = ((unsigned int)u) << 16;
  return cv.f;
}
__device__ __forceinline__ f32x4 mfma_bf16(short8 a, short8 b, f32x4 c) {
  return __builtin_amdgcn_mfma_f32_16x16x32_bf16(a, b, c, 0, 0, 0);
}
// 3-term compensated product: ah*bh + ah*bl + al*bh  (error ~2^-16)
__device__ __forceinline__ f32x4 mfma3(short8 ah, short8 al, short8 bh, short8 bl, f32x4 c) {
  c = mfma_bf16(ah, bh, c);
  c = mfma_bf16(ah, bl, c);
  c = mfma_bf16(al, bh, c);
  return c;
}
// LDS-only barrier: drains LDS ops for cross-wave visibility; in-flight
// global loads survive (no vmcnt(0) drain).
__device__ __forceinline__ void bar_lds() {
  asm volatile("s_waitcnt lgkmcnt(0)" ::: "memory");
  __builtin_amdgcn_s_barrier();
}

// ---------------------------------------------------------------------------
// Fused projection: from x compute
//   Qh/Ql = bf16 hi/lo of x@Wq^T   (row-major [N][D])
//   Kh/Kl = bf16 hi/lo of x@Wk^T   (row-major [N][D])
//   VTh   = bf16 hi     of (x@Wv^T)^T  ([D][N])
// One x-tile staging, 3 W tiles in LDS, 3 accumulator sets (3x ILP).
// ---------------------------------------------------------------------------
__global__ __launch_bounds__(256) void proj_fused(
    const float* __restrict__ x, const float* __restrict__ Wq,
    const float* __restrict__ Wk, const float* __restrict__ Wv,
    ushort* __restrict__ Qh, ushort* __restrict__ Ql,
    ushort* __restrict__ Kh, ushort* __restrict__ Kl,
    ushort* __restrict__ VTh)
{
  __shared__ float Xs[64][33];
  __shared__ float Ws[3][32][68];
  const int tid = threadIdx.x;
  const int tx = tid & 15;
  const int ty = tid >> 4;
  const int i0 = blockIdx.x * 64;
  const int j0 = blockIdx.y * 64;
  float aq[4][4] = {}, ak[4][4] = {}, av[4][4] = {};

  const float* Wm[3] = {Wq, Wk, Wv};

  for (int k0 = 0; k0 < kD; k0 += 32) {
#pragma unroll
    for (int s = 0; s < 2; ++s) {
      const int f = tid + 256 * s;
      const int row = f >> 3;
      const int c4 = (f & 7) * 4;
      const float4 v = *reinterpret_cast<const float4*>(
          &x[(size_t)(i0 + row) * kD + k0 + c4]);
      Xs[row][c4 + 0] = v.x; Xs[row][c4 + 1] = v.y;
      Xs[row][c4 + 2] = v.z; Xs[row][c4 + 3] = v.w;
    }
#pragma unroll
    for (int m = 0; m < 3; ++m) {
#pragma unroll
      for (int s = 0; s < 2; ++s) {
        const int f = tid + 256 * s;
        const int col = f >> 3;
        const int c4 = (f & 7) * 4;
        const float4 v = *reinterpret_cast<const float4*>(
            &Wm[m][(size_t)(j0 + col) * kD + k0 + c4]);
        Ws[m][c4 + 0][col] = v.x; Ws[m][c4 + 1][col] = v.y;
        Ws[m][c4 + 2][col] = v.z; Ws[m][c4 + 3][col] = v.w;
      }
    }
    __syncthreads();
#pragma unroll
    for (int kk = 0; kk < 32; ++kk) {
      const float4 bq = *reinterpret_cast<const float4*>(&Ws[0][kk][tx * 4]);
      const float4 bk = *reinterpret_cast<const float4*>(&Ws[1][kk][tx * 4]);
      const float4 bv = *reinterpret_cast<const float4*>(&Ws[2][kk][tx * 4]);
#pragma unroll
      for (int r = 0; r < 4; ++r) {
        const float a = Xs[ty * 4 + r][kk];
        aq[r][0] += a * bq.x; aq[r][1] += a * bq.y; aq[r][2] += a * bq.z; aq[r][3] += a * bq.w;
        ak[r][0] += a * bk.x; ak[r][1] += a * bk.y; ak[r][2] += a * bk.z; ak[r][3] += a * bk.w;
        av[r][0] += a * bv.x; av[r][1] += a * bv.y; av[r][2] += a * bv.z; av[r][3] += a * bv.w;
      }
    }
    __syncthreads();
  }

  // Q, K: row-major hi/lo
#pragma unroll
  for (int r = 0; r < 4; ++r) {
    ushort4 qh, ql, kh, kl;
    ushort* qhp = &qh.x; ushort* qlp = &ql.x;
    ushort* khp = &kh.x; ushort* klp = &kl.x;
#pragma unroll
    for (int c = 0; c < 4; ++c) {
      const float fq = aq[r][c];
      const ushort hq = f2bf(fq);
      qhp[c] = hq; qlp[c] = f2bf(fq - bf2f(hq));
      const float fk = ak[r][c];
      const ushort hk = f2bf(fk);
      khp[c] = hk; klp[c] = f2bf(fk - bf2f(hk));
    }
    const int oi = (i0 + ty * 4 + r) * kD + j0 + tx * 4;
    *reinterpret_cast<ushort4*>(&Qh[oi]) = qh;
    *reinterpret_cast<ushort4*>(&Ql[oi]) = ql;
    *reinterpret_cast<ushort4*>(&Kh[oi]) = kh;
    *reinterpret_cast<ushort4*>(&Kl[oi]) = kl;
  }
  // V: transposed, hi only
#pragma unroll
  for (int c = 0; c < 4; ++c) {
    ushort4 h;
    ushort* hp = &h.x;
#pragma unroll
    for (int r = 0; r < 4; ++r) hp[r] = f2bf(av[r][c]);
    const int oi = (j0 + tx * 4 + c) * kN + i0 + ty * 4;
    *reinterpret_cast<ushort4*>(&VTh[oi]) = h;
  }
}

// ---------------------------------------------------------------------------
// MFMA flash attention v8: r4 structure + BATCHED loads (issue-all, wait-once).
// BM=64, 512 threads (8 waves), SPLIT=2 -> grid (2,128)=256 blocks.
// S^T = mfma3(K,Q): wave w owns keys [16w,16w+16), all 64 q-rows (qt=0..3).
// S phase: 24 K-frag loads batch-issued into transient regs, sched_barrier,
// then 144 MFMAs. PV: 12 V-frag loads batched, then 48 MFMAs (P*Vh, 1-term).
// Q hi+lo staged once in LDS; P hi-only in LDS; 2 LDS-only barriers/tile.
// LDS: Qh 49K | Ql 49K | P 17.4K | MLB 4K -> 1 block/CU, 8 waves.
// ---------------------------------------------------------------------------
static constexpr int SPLITf = 2;
static constexpr int KEYSf = kN / SPLITf;   // 4096
static constexpr int NTIL = KEYSf / 128;    // 32

static constexpr int OFF_QH = 0;       // ushort offsets into LDSU
static constexpr int OFF_QL = 25088;   // 64*392
static constexpr int OFF_P  = 50176;

__global__ __launch_bounds__(512, 2) void flash_mfma(
    const ushort* __restrict__ Qh, const ushort* __restrict__ Ql,
    const ushort* __restrict__ Kh, const ushort* __restrict__ Kl,
    const ushort* __restrict__ VTh,
    float* __restrict__ Opart, float* __restrict__ ml)
{
  __shared__ ushort LDSU[58880];   // 117760 B
  __shared__ float MLB[1024];      // m: [0,512), l: [512,1024)

  const int tid = threadIdx.x;
  const int w = tid >> 6;
  const int lane = tid & 63;
  const int l15 = lane & 15;
  const int hi4 = lane >> 4;
  const int sp = blockIdx.x;
  const int i0 = blockIdx.y * 64;
  const int kg0 = sp * KEYSf;

  // ---- stage Q-hi + Q-lo once ----
  {
    const int row = tid >> 3;
    const int sg = (tid & 7) * 48;
    const ushort* sh = Qh + (size_t)(i0 + row) * kD + sg;
    const ushort* sl = Ql + (size_t)(i0 + row) * kD + sg;
    ushort* dh = LDSU + OFF_QH + row * 392 + sg;
    ushort* dl = LDSU + OFF_QL + row * 392 + sg;
#pragma unroll
    for (int u = 0; u < 6; ++u) {
      *reinterpret_cast<uint4*>(dh + 8 * u) =
          *reinterpret_cast<const uint4*>(sh + 8 * u);
      *reinterpret_cast<uint4*>(dl + 8 * u) =
          *reinterpret_cast<const uint4*>(sl + 8 * u);
    }
  }

  const f32x4 zf = {0.f, 0.f, 0.f, 0.f};
  f32x4 o[4][3];
#pragma unroll
  for (int qt = 0; qt < 4; ++qt)
#pragma unroll
    for (int c = 0; c < 3; ++c) o[qt][c] = zf;
  float m_run[4], l_run[4];
#pragma unroll
  for (int qt = 0; qt < 4; ++qt) { m_run[qt] = -INFINITY; l_run[qt] = 0.f; }

  __syncthreads();   // Q staged

  for (int kb = 0; kb < NTIL; ++kb) {
    const int kg = kg0 + kb * 128;

    // ---- batch-issue ALL 24 K-frag loads (transient regs) ----
    short8 ka[12], kc[12];
    {
      const size_t kbase = (size_t)(kg + 16 * w + l15) * kD + 8 * hi4;
#pragma unroll
      for (int ks = 0; ks < 12; ++ks) {
        ka[ks] = *reinterpret_cast<const short8*>(Kh + kbase + 32 * ks);
        kc[ks] = *reinterpret_cast<const short8*>(Kl + kbase + 32 * ks);
      }
    }
    __builtin_amdgcn_sched_barrier(0);   // keep loads batched above MFMAs

    // ---- S phase: K from regs, Q hi/lo from LDS ----
    f32x4 sacc[4];
#pragma unroll
    for (int qt = 0; qt < 4; ++qt) sacc[qt] = zf;
#pragma unroll
    for (int ks = 0; ks < 12; ++ks) {
      const int d0 = 32 * ks;
#pragma unroll
      for (int qt = 0; qt < 4; ++qt) {
        const int qoff = (16 * qt + l15) * 392 + d0 + 8 * hi4;
        const short8 qh = *reinterpret_cast<const short8*>(LDSU + OFF_QH + qoff);
        const short8 ql = *reinterpret_cast<const short8*>(LDSU + OFF_QL + qoff);
        sacc[qt] = mfma3(ka[ks], kc[ks], qh, ql, sacc[qt]);
      }
    }

    // ---- online softmax ----
    float mt4[4];
#pragma unroll
    for (int qt = 0; qt < 4; ++qt) {
      float mt = fmaxf(fmaxf(sacc[qt][0], sacc[qt][1]),
                       fmaxf(sacc[qt][2], sacc[qt][3]));
      mt = fmaxf(mt, __shfl_xor(mt, 16, 64));
      mt = fmaxf(mt, __shfl_xor(mt, 32, 64));
      mt4[qt] = mt;
    }
    if (lane < 16) {
#pragma unroll
      for (int qt = 0; qt < 4; ++qt) MLB[w * 64 + qt * 16 + l15] = mt4[qt];
    }
    bar_lds();  // B1
    float sc[4];
#pragma unroll
    for (int qt = 0; qt < 4; ++qt) {
      float Mt = MLB[qt * 16 + l15];
#pragma unroll
      for (int w2 = 1; w2 < 8; ++w2)
        Mt = fmaxf(Mt, MLB[w2 * 64 + qt * 16 + l15]);
      const float mnew = fmaxf(m_run[qt], Mt);
      sc[qt] = __expf(m_run[qt] - mnew);
      m_run[qt] = mnew;
      const float p0 = __expf(sacc[qt][0] - mnew);
      const float p1 = __expf(sacc[qt][1] - mnew);
      const float p2 = __expf(sacc[qt][2] - mnew);
      const float p3 = __expf(sacc[qt][3] - mnew);
      float ls = (p0 + p1) + (p2 + p3);
      ls += __shfl_xor(ls, 16, 64);
      ls += __shfl_xor(ls, 32, 64);
      if (lane < 16) MLB[512 + w * 64 + qt * 16 + l15] = ls;
      // pack P -> bf16 hi only, one b64 write
      uint2 HH;
      HH.x = (unsigned int)f2bf(p0) | ((unsigned int)f2bf(p1) << 16);
      HH.y = (unsigned int)f2bf(p2) | ((unsigned int)f2bf(p3) << 16);
      const int pi = (16 * qt + l15) * 136 + 16 * w + 4 * hi4;
      *reinterpret_cast<uint2*>(LDSU + OFF_P + pi) = HH;
      // rescale O (row of o = qrow 16qt+4*hi4+r)
#pragma unroll
      for (int r = 0; r < 4; ++r) {
        const float scr_ = __shfl(sc[qt], 4 * hi4 + r, 64);
#pragma unroll
        for (int c = 0; c < 3; ++c) o[qt][c][r] *= scr_;
      }
    }
    bar_lds();  // B2: P + mlb_l ready
#pragma unroll
    for (int qt = 0; qt < 4; ++qt) {
      float acc = MLB[512 + qt * 16 + l15];
#pragma unroll
      for (int w2 = 1; w2 < 8; ++w2) acc += MLB[512 + w2 * 64 + qt * 16 + l15];
      l_run[qt] = l_run[qt] * sc[qt] + acc;
    }

    // ---- PV: batch-issue ALL 12 V-frag loads, then 48 MFMAs ----
    short8 vv[12];
#pragma unroll
    for (int c = 0; c < 3; ++c)
#pragma unroll
      for (int kv = 0; kv < 4; ++kv)
        vv[c * 4 + kv] = *reinterpret_cast<const short8*>(
            VTh + (size_t)(48 * w + 16 * c + l15) * kN + kg + 32 * kv + 8 * hi4);
    __builtin_amdgcn_sched_barrier(0);
#pragma unroll
    for (int kv = 0; kv < 4; ++kv) {
      short8 pf0 = *reinterpret_cast<const short8*>(
          LDSU + OFF_P + (l15)*136 + 32 * kv + 8 * hi4);
      short8 pf1 = *reinterpret_cast<const short8*>(
          LDSU + OFF_P + (16 + l15) * 136 + 32 * kv + 8 * hi4);
      short8 pf2 = *reinterpret_cast<const short8*>(
          LDSU + OFF_P + (32 + l15) * 136 + 32 * kv + 8 * hi4);
      short8 pf3 = *reinterpret_cast<const short8*>(
          LDSU + OFF_P + (48 + l15) * 136 + 32 * kv + 8 * hi4);
#pragma unroll
      for (int c = 0; c < 3; ++c) {
        o[0][c] = mfma_bf16(pf0, vv[c * 4 + kv], o[0][c]);
        o[1][c] = mfma_bf16(pf1, vv[c * 4 + kv], o[1][c]);
        o[2][c] = mfma_bf16(pf2, vv[c * 4 + kv], o[2][c]);
        o[3][c] = mfma_bf16(pf3, vv[c * 4 + kv], o[3][c]);
      }
    }
  }

  // ---- write unnormalized partials + (m,l); waves own disjoint d-cols ----
#pragma unroll
  for (int qt = 0; qt < 4; ++qt)
#pragma unroll
    for (int c = 0; c < 3; ++c)
#pragma unroll
      for (int r = 0; r < 4; ++r)
        Opart[(size_t)sp * kND + (i0 + 16 * qt + 4 * hi4 + r) * kD +
              48 * w + 16 * c + l15] = o[qt][c][r];
  if (w == 0 && lane < 16) {
#pragma unroll
    for (int qt = 0; qt < 4; ++qt) {
      const int mi = (sp * kN + i0 + 16 * qt + l15) * 2;
      ml[mi] = m_run[qt];
      ml[mi + 1] = l_run[qt];
    }
  }
}

// ---------------------------------------------------------------------------
// Merge 2 key-split partials
// ---------------------------------------------------------------------------
__global__ __launch_bounds__(256) void merge_kernel(
    const float* __restrict__ Opart, const float* __restrict__ ml,
    float* __restrict__ O)
{
  const size_t idx = (size_t)blockIdx.x * 256 + threadIdx.x;
  const size_t i = idx / kD;
  const float m0 = ml[i * 2];
  const float l0 = ml[i * 2 + 1];
  const float m1 = ml[((size_t)kN + i) * 2];
  const float l1 = ml[((size_t)kN + i) * 2 + 1];
  const float m = fmaxf(m0, m1);
  const float e0 = expf(m0 - m);
  const float e1 = expf(m1 - m);
  const float inv = 1.0f / (e0 * l0 + e1 * l1);
  O[idx] = (e0 * Opart[idx] + e1 * Opart[(size_t)kND + idx]) * inv;
}

// ---------------------------------------------------------------------------
// Layer-2: exact matvec formulation (no full GEMMs).
// ---------------------------------------------------------------------------
__global__ __launch_bounds__(64) void qrow_kernel(
    const float* __restrict__ h1, const float* __restrict__ Wq,
    float* __restrict__ q2)
{
  const int j = blockIdx.x;
  const int lane = threadIdx.x;
  const float* hr = h1 + (size_t)(kN - 1) * kD;
  float acc = 0.f;
  for (int d = lane; d < kD; d += 64) acc += hr[d] * Wq[(size_t)j * kD + d];
#pragma unroll
  for (int off = 32; off > 0; off >>= 1) acc += __shfl_xor(acc, off, 64);
  if (lane == 0) q2[j] = acc;
}

__global__ __launch_bounds__(384) void u_kernel(
    const float* __restrict__ Wk, const float* __restrict__ q2,
    float* __restrict__ u)
{
  __shared__ float qs[kD];
  const int d = threadIdx.x;
  qs[d] = q2[d];
  __syncthreads();
  float acc = 0.f;
  for (int k = 0; k < kD; ++k) acc += Wk[(size_t)k * kD + d] * qs[k];
  u[d] = acc;
}

__global__ __launch_bounds__(256) void logits_kernel(
    const float* __restrict__ h1, const float* __restrict__ u,
    float* __restrict__ lg)
{
  const int wave = threadIdx.x >> 6;
  const int lane = threadIdx.x & 63;
  const int j = blockIdx.x * 4 + wave;
  float acc = 0.f;
#pragma unroll
  for (int t = 0; t < kD / 64; ++t) {
    const int d = lane + t * 64;
    acc += h1[(size_t)j * kD + d] * u[d];
  }
#pragma unroll
  for (int off = 32; off > 0; off >>= 1) acc += __shfl_xor(acc, off, 64);
  if (lane == 0) lg[j] = acc;
}

__global__ __launch_bounds__(1024) void smax_kernel(
    const float* __restrict__ lg, float* __restrict__ wgt)
{
  __shared__ float red[16];
  const int t = threadIdx.x;
  const int wave = t >> 6;
  const int lane = t & 63;
  float v[8];
  float mx = -INFINITY;
#pragma unroll
  for (int s = 0; s < 8; ++s) {
    v[s] = lg[t + 1024 * s];
    mx = fmaxf(mx, v[s]);
  }
#pragma unroll
  for (int off = 32; off > 0; off >>= 1) mx = fmaxf(mx, __shfl_xor(mx, off, 64));
  if (lane == 0) red[wave] = mx;
  __syncthreads();
  if (t == 0) {
    float m = red[0];
    for (int i = 1; i < 16; ++i) m = fmaxf(m, red[i]);
    red[0] = m;
  }
  __syncthreads();
  const float m = red[0];
  __syncthreads();
  float sum = 0.f;
#pragma unroll
  for (int s = 0; s < 8; ++s) {
    v[s] = expf(v[s] - m);
    sum += v[s];
  }
#pragma unroll
  for (int off = 32; off > 0; off >>= 1) sum += __shfl_xor(sum, off, 64);
  if (lane == 0) red[wave] = sum;
  __syncthreads();
  if (t == 0) {
    float S = 0.f;
    for (int i = 0; i < 16; ++i) S += red[i];
    red[0] = S;
  }
  __syncthreads();
  const float invS = 1.0f / red[0];
#pragma unroll
  for (int s = 0; s < 8; ++s) wgt[t + 1024 * s] = v[s] * invS;
}

// part[b][d] = sum_{j in block b's 256 rows} wgt[j] * h1[j][d]
__global__ __launch_bounds__(384) void wsum_kernel(
    const float* __restrict__ wgt, const float* __restrict__ h1,
    float* __restrict__ part)
{
  __shared__ float wl[256];
  const int b = blockIdx.x;
  const int t = threadIdx.x;
  if (t < 256) wl[t] = wgt[b * 256 + t];
  __syncthreads();
  const float* Hp = h1 + (size_t)b * 256 * kD;
  float acc = 0.f;
  for (int j = 0; j < 256; ++j) acc += wl[j] * Hp[(size_t)j * kD + t];
  part[b * kD + t] = acc;
}

__global__ __launch_bounds__(384) void final2_kernel(
    const float* __restrict__ part, const float* __restrict__ Wv,
    const float* __restrict__ ffws, float* __restrict__ out)
{
  __shared__ float zs[kD];
  __shared__ float red[6];
  const int t = threadIdx.x;
  const int wave = t >> 6;
  const int lane = t & 63;
  float z = 0.f;
#pragma unroll
  for (int b = 0; b < 32; ++b) z += part[b * kD + t];
  zs[t] = z;
  __syncthreads();
  float zv = 0.f;
  for (int k = 0; k < kD; ++k) zv += Wv[(size_t)t * kD + k] * zs[k];
  float val = zv * ffws[t];
#pragma unroll
  for (int off = 32; off > 0; off >>= 1) val += __shfl_xor(val, off, 64);
  if (lane == 0) red[wave] = val;
  __syncthreads();
  if (t == 0) {
    float s = red[0];
    for (int i = 1; i < 6; ++i) s += red[i];
    out[0] = 1.0f / (1.0f + expf(-s));
  }
}

// ---------------------------------------------------------------------------
extern "C" void kernel_launch(void* const* d_in, const int* in_sizes, int n_in,
                              void* d_out, int out_size, void* d_ws, size_t ws_size,
                              hipStream_t stream) {
  const float* x    = (const float*)d_in[0];
  const float* Wq   = (const float*)d_in[1];
  const float* Wk   = (const float*)d_in[2];
  const float* Wv   = (const float*)d_in[3];
  const float* ffws = (const float*)d_in[4];
  float* out = (float*)d_out;
  char* wsb = (char*)d_ws;

  ushort* Qh  = (ushort*)wsb;
  ushort* Ql  = Qh + kND;
  ushort* Kh  = Ql + kND;
  ushort* Kl  = Kh + kND;
  ushort* VTh = Kl + kND;
  const size_t bfQKV = 5 * (size_t)kND * 2;
  float* Opart = (float*)(wsb + bfQKV);
  float* ml    = Opart + 2 * (size_t)kND;
  float* h1    = ml + 4 * (size_t)kN;
  float* q2    = h1 + (size_t)kND;
  float* u     = q2 + kD;
  float* lg    = u + kD;
  float* wgt   = lg + kN;
  float* part  = wgt + kN;

  // fused layer-1 projections -> bf16 operands (Q,K hi/lo; V^T hi)
  proj_fused<<<dim3(kN / 64, kD / 64), 256, 0, stream>>>(
      x, Wq, Wk, Wv, Qh, Ql, Kh, Kl, VTh);
  // layer-1 attention
  flash_mfma<<<dim3(SPLITf, kN / 64), 512, 0, stream>>>(
      Qh, Ql, Kh, Kl, VTh, Opart, ml);
  merge_kernel<<<(kN * kD) / 256, 256, 0, stream>>>(Opart, ml, h1);
  // layer-2 (exact matvec chain)
  qrow_kernel<<<kD, 64, 0, stream>>>(h1, Wq, q2);
  u_kernel<<<1, 384, 0, stream>>>(Wk, q2, u);
  logits_kernel<<<kN / 4, 256, 0, stream>>>(h1, u, lg);
  smax_kernel<<<1, 1024, 0, stream>>>(lg, wgt);
  wsum_kernel<<<32, 384, 0, stream>>>(wgt, h1, part);
  final2_kernel<<<1, 384, 0, stream>>>(part, Wv, ffws, out);
}

// Round 9
// 362.825 us; speedup vs baseline: 2.4639x; 1.3720x over previous
//
#include <hip/hip_runtime.h>
#include <hip/hip_bf16.h>
#include <math.h>

static constexpr int kN = 8192;
static constexpr int kD = 384;
static constexpr int kND = kN * kD;

typedef __attribute__((ext_vector_type(8))) short short8;
typedef __attribute__((ext_vector_type(4))) float f32x4;

// ---- bf16 helpers (bit-exact RNE) ----
__device__ __forceinline__ ushort f2bf(float f) {
  union { float f; unsigned int i; } cv; cv.f = f;
  unsigned int lsb = (cv.i >> 16) & 1u;
  unsigned int r = cv.i + 0x7fffu + lsb;
  return (ushort)(r >> 16);
}
__device__ __forceinline__ float bf2f(ushort u) {
  union { unsigned int i; float f; } cv; cv.i = ((unsigned int)u) << 16;
  return cv.f;
}
__device__ __forceinline__ f32x4 mfma_bf16(short8 a, short8 b, f32x4 c) {
  return __builtin_amdgcn_mfma_f32_16x16x32_bf16(a, b, c, 0, 0, 0);
}
// LDS-only barrier: drains LDS ops for cross-wave visibility; in-flight
// global loads survive (no vmcnt(0) drain).
__device__ __forceinline__ void bar_lds() {
  asm volatile("s_waitcnt lgkmcnt(0)" ::: "memory");
  __builtin_amdgcn_s_barrier();
}

// ---------------------------------------------------------------------------
// Fused projection: from x compute
//   Qh    = bf16 hi of x@Wq^T        (row-major [N][D])
//   Kh/Kl = bf16 hi/lo of x@Wk^T     (row-major [N][D])
//   VTh   = bf16 hi of (x@Wv^T)^T    ([D][N])
// ---------------------------------------------------------------------------
__global__ __launch_bounds__(256) void proj_fused(
    const float* __restrict__ x, const float* __restrict__ Wq,
    const float* __restrict__ Wk, const float* __restrict__ Wv,
    ushort* __restrict__ Qh,
    ushort* __restrict__ Kh, ushort* __restrict__ Kl,
    ushort* __restrict__ VTh)
{
  __shared__ float Xs[64][33];
  __shared__ float Ws[3][32][68];
  const int tid = threadIdx.x;
  const int tx = tid & 15;
  const int ty = tid >> 4;
  const int i0 = blockIdx.x * 64;
  const int j0 = blockIdx.y * 64;
  float aq[4][4] = {}, ak[4][4] = {}, av[4][4] = {};

  const float* Wm[3] = {Wq, Wk, Wv};

  for (int k0 = 0; k0 < kD; k0 += 32) {
#pragma unroll
    for (int s = 0; s < 2; ++s) {
      const int f = tid + 256 * s;
      const int row = f >> 3;
      const int c4 = (f & 7) * 4;
      const float4 v = *reinterpret_cast<const float4*>(
          &x[(size_t)(i0 + row) * kD + k0 + c4]);
      Xs[row][c4 + 0] = v.x; Xs[row][c4 + 1] = v.y;
      Xs[row][c4 + 2] = v.z; Xs[row][c4 + 3] = v.w;
    }
#pragma unroll
    for (int m = 0; m < 3; ++m) {
#pragma unroll
      for (int s = 0; s < 2; ++s) {
        const int f = tid + 256 * s;
        const int col = f >> 3;
        const int c4 = (f & 7) * 4;
        const float4 v = *reinterpret_cast<const float4*>(
            &Wm[m][(size_t)(j0 + col) * kD + k0 + c4]);
        Ws[m][c4 + 0][col] = v.x; Ws[m][c4 + 1][col] = v.y;
        Ws[m][c4 + 2][col] = v.z; Ws[m][c4 + 3][col] = v.w;
      }
    }
    __syncthreads();
#pragma unroll
    for (int kk = 0; kk < 32; ++kk) {
      const float4 bq = *reinterpret_cast<const float4*>(&Ws[0][kk][tx * 4]);
      const float4 bk = *reinterpret_cast<const float4*>(&Ws[1][kk][tx * 4]);
      const float4 bv = *reinterpret_cast<const float4*>(&Ws[2][kk][tx * 4]);
#pragma unroll
      for (int r = 0; r < 4; ++r) {
        const float a = Xs[ty * 4 + r][kk];
        aq[r][0] += a * bq.x; aq[r][1] += a * bq.y; aq[r][2] += a * bq.z; aq[r][3] += a * bq.w;
        ak[r][0] += a * bk.x; ak[r][1] += a * bk.y; ak[r][2] += a * bk.z; ak[r][3] += a * bk.w;
        av[r][0] += a * bv.x; av[r][1] += a * bv.y; av[r][2] += a * bv.z; av[r][3] += a * bv.w;
      }
    }
    __syncthreads();
  }

  // Q: row-major hi only; K: row-major hi/lo
#pragma unroll
  for (int r = 0; r < 4; ++r) {
    ushort4 qh, kh, kl;
    ushort* qhp = &qh.x;
    ushort* khp = &kh.x; ushort* klp = &kl.x;
#pragma unroll
    for (int c = 0; c < 4; ++c) {
      qhp[c] = f2bf(aq[r][c]);
      const float fk = ak[r][c];
      const ushort hk = f2bf(fk);
      khp[c] = hk; klp[c] = f2bf(fk - bf2f(hk));
    }
    const int oi = (i0 + ty * 4 + r) * kD + j0 + tx * 4;
    *reinterpret_cast<ushort4*>(&Qh[oi]) = qh;
    *reinterpret_cast<ushort4*>(&Kh[oi]) = kh;
    *reinterpret_cast<ushort4*>(&Kl[oi]) = kl;
  }
  // V: transposed, hi only
#pragma unroll
  for (int c = 0; c < 4; ++c) {
    ushort4 h;
    ushort* hp = &h.x;
#pragma unroll
    for (int r = 0; r < 4; ++r) hp[r] = f2bf(av[r][c]);
    const int oi = (j0 + tx * 4 + c) * kN + i0 + ty * 4;
    *reinterpret_cast<ushort4*>(&VTh[oi]) = h;
  }
}

// ---------------------------------------------------------------------------
// MFMA flash attention v9: BM=128 q-rows/block (halves K/V L3 traffic),
// 512 threads (8 waves), SPLIT=4 -> grid (4,64)=256 blocks, 1 block/CU.
// S^T = mfma(K,Q): wave w owns keys [16w,16w+16), all 128 q-rows (qt=0..7).
//   S = kh*qh + kl*qh  (K full hi/lo from global, Q hi-only from LDS;
//   dropped ql*k term ~2^-9 — see round theory for safety argument).
// K batched in 2 halves of 6 frags (limits transient VGPR). PV: V-frags
// batched from global VT (wave w owns d-cols [48w,48w+48)), P hi in LDS.
// LDS: Qh 100K | P 34.8K | MLB 8K = 143K.
// ---------------------------------------------------------------------------
static constexpr int SPLITf = 4;
static constexpr int KEYSf = kN / SPLITf;   // 2048
static constexpr int NTIL = KEYSf / 128;    // 16

static constexpr int OFF_QH = 0;        // ushort offsets into LDSU
static constexpr int OFF_P  = 50176;    // 128*392

__global__ __launch_bounds__(512, 2) void flash_mfma(
    const ushort* __restrict__ Qh,
    const ushort* __restrict__ Kh, const ushort* __restrict__ Kl,
    const ushort* __restrict__ VTh,
    float* __restrict__ Opart, float* __restrict__ ml)
{
  __shared__ ushort LDSU[67584];   // 135168 B (Qh 128x392 | P 128x136)
  __shared__ float MLB[2048];      // m: [0,1024), l: [1024,2048)

  const int tid = threadIdx.x;
  const int w = tid >> 6;
  const int lane = tid & 63;
  const int l15 = lane & 15;
  const int hi4 = lane >> 4;
  const int sp = blockIdx.x;
  const int i0 = blockIdx.y * 128;
  const int kg0 = sp * KEYSf;

  // ---- stage Q-hi once: 128 rows, stride 392 ushorts ----
  {
    const int row = tid >> 2;            // 0..127
    const int sg = (tid & 3) * 96;       // 96 ushorts = 12 x uint4
    const ushort* sh = Qh + (size_t)(i0 + row) * kD + sg;
    ushort* dh = LDSU + OFF_QH + row * 392 + sg;
#pragma unroll
    for (int u = 0; u < 12; ++u)
      *reinterpret_cast<uint4*>(dh + 8 * u) =
          *reinterpret_cast<const uint4*>(sh + 8 * u);
  }

  const f32x4 zf = {0.f, 0.f, 0.f, 0.f};
  f32x4 o[8][3];
#pragma unroll
  for (int qt = 0; qt < 8; ++qt)
#pragma unroll
    for (int c = 0; c < 3; ++c) o[qt][c] = zf;
  float m_run[8], l_run[8];
#pragma unroll
  for (int qt = 0; qt < 8; ++qt) { m_run[qt] = -INFINITY; l_run[qt] = 0.f; }

  __syncthreads();   // Q staged

  for (int kb = 0; kb < NTIL; ++kb) {
    const int kg = kg0 + kb * 128;

    // ---- S phase: K hi/lo batch-loaded in 2 halves, Q hi from LDS ----
    f32x4 sacc[8];
#pragma unroll
    for (int qt = 0; qt < 8; ++qt) sacc[qt] = zf;
    const size_t kbase = (size_t)(kg + 16 * w + l15) * kD + 8 * hi4;
#pragma unroll
    for (int half = 0; half < 2; ++half) {
      short8 ka[6], kc[6];
#pragma unroll
      for (int j = 0; j < 6; ++j) {
        ka[j] = *reinterpret_cast<const short8*>(Kh + kbase + 32 * (6 * half + j));
        kc[j] = *reinterpret_cast<const short8*>(Kl + kbase + 32 * (6 * half + j));
      }
      __builtin_amdgcn_sched_barrier(0);   // keep loads batched above MFMAs
#pragma unroll
      for (int j = 0; j < 6; ++j) {
        const int d0 = 32 * (6 * half + j);
#pragma unroll
        for (int qt = 0; qt < 8; ++qt) {
          const short8 qh = *reinterpret_cast<const short8*>(
              LDSU + OFF_QH + (16 * qt + l15) * 392 + d0 + 8 * hi4);
          sacc[qt] = mfma_bf16(ka[j], qh, sacc[qt]);
          sacc[qt] = mfma_bf16(kc[j], qh, sacc[qt]);
        }
      }
    }

    // ---- online softmax (8 q-tiles) ----
    float mt8[8];
#pragma unroll
    for (int qt = 0; qt < 8; ++qt) {
      float mt = fmaxf(fmaxf(sacc[qt][0], sacc[qt][1]),
                       fmaxf(sacc[qt][2], sacc[qt][3]));
      mt = fmaxf(mt, __shfl_xor(mt, 16, 64));
      mt = fmaxf(mt, __shfl_xor(mt, 32, 64));
      mt8[qt] = mt;
    }
    if (lane < 16) {
#pragma unroll
      for (int qt = 0; qt < 8; ++qt) MLB[w * 128 + qt * 16 + l15] = mt8[qt];
    }
    bar_lds();  // B1
    float sc[8];
#pragma unroll
    for (int qt = 0; qt < 8; ++qt) {
      float Mt = MLB[qt * 16 + l15];
#pragma unroll
      for (int w2 = 1; w2 < 8; ++w2)
        Mt = fmaxf(Mt, MLB[w2 * 128 + qt * 16 + l15]);
      const float mnew = fmaxf(m_run[qt], Mt);
      sc[qt] = __expf(m_run[qt] - mnew);
      m_run[qt] = mnew;
      const float p0 = __expf(sacc[qt][0] - mnew);
      const float p1 = __expf(sacc[qt][1] - mnew);
      const float p2 = __expf(sacc[qt][2] - mnew);
      const float p3 = __expf(sacc[qt][3] - mnew);
      float ls = (p0 + p1) + (p2 + p3);
      ls += __shfl_xor(ls, 16, 64);
      ls += __shfl_xor(ls, 32, 64);
      if (lane < 16) MLB[1024 + w * 128 + qt * 16 + l15] = ls;
      // pack P -> bf16 hi, one b64 write
      uint2 HH;
      HH.x = (unsigned int)f2bf(p0) | ((unsigned int)f2bf(p1) << 16);
      HH.y = (unsigned int)f2bf(p2) | ((unsigned int)f2bf(p3) << 16);
      const int pi = (16 * qt + l15) * 136 + 16 * w + 4 * hi4;
      *reinterpret_cast<uint2*>(LDSU + OFF_P + pi) = HH;
      // rescale O (row of o = qrow 16qt+4*hi4+r)
#pragma unroll
      for (int r = 0; r < 4; ++r) {
        const float scr_ = __shfl(sc[qt], 4 * hi4 + r, 64);
#pragma unroll
        for (int c = 0; c < 3; ++c) o[qt][c][r] *= scr_;
      }
    }
    bar_lds();  // B2: P + mlb_l ready
#pragma unroll
    for (int qt = 0; qt < 8; ++qt) {
      float acc = MLB[1024 + qt * 16 + l15];
#pragma unroll
      for (int w2 = 1; w2 < 8; ++w2)
        acc += MLB[1024 + w2 * 128 + qt * 16 + l15];
      l_run[qt] = l_run[qt] * sc[qt] + acc;
    }

    // ---- PV: batch-issue 12 V-frag loads, then 96 MFMAs ----
    short8 vv[12];
#pragma unroll
    for (int c = 0; c < 3; ++c)
#pragma unroll
      for (int kv = 0; kv < 4; ++kv)
        vv[c * 4 + kv] = *reinterpret_cast<const short8*>(
            VTh + (size_t)(48 * w + 16 * c + l15) * kN + kg + 32 * kv + 8 * hi4);
    __builtin_amdgcn_sched_barrier(0);
#pragma unroll
    for (int kv = 0; kv < 4; ++kv) {
      short8 pf[8];
#pragma unroll
      for (int qt = 0; qt < 8; ++qt)
        pf[qt] = *reinterpret_cast<const short8*>(
            LDSU + OFF_P + (16 * qt + l15) * 136 + 32 * kv + 8 * hi4);
#pragma unroll
      for (int c = 0; c < 3; ++c) {
#pragma unroll
        for (int qt = 0; qt < 8; ++qt)
          o[qt][c] = mfma_bf16(pf[qt], vv[c * 4 + kv], o[qt][c]);
      }
    }
  }

  // ---- write unnormalized partials + (m,l); waves own disjoint d-cols ----
#pragma unroll
  for (int qt = 0; qt < 8; ++qt)
#pragma unroll
    for (int c = 0; c < 3; ++c)
#pragma unroll
      for (int r = 0; r < 4; ++r)
        Opart[(size_t)sp * kND + (i0 + 16 * qt + 4 * hi4 + r) * kD +
              48 * w + 16 * c + l15] = o[qt][c][r];
  if (w == 0 && lane < 16) {
#pragma unroll
    for (int qt = 0; qt < 8; ++qt) {
      const int mi = (sp * kN + i0 + 16 * qt + l15) * 2;
      ml[mi] = m_run[qt];
      ml[mi + 1] = l_run[qt];
    }
  }
}

// ---------------------------------------------------------------------------
// Merge 4 key-split partials (unnormalized + per-split (m,l))
// ---------------------------------------------------------------------------
__global__ __launch_bounds__(256) void merge_kernel(
    const float* __restrict__ Opart, const float* __restrict__ ml,
    float* __restrict__ O)
{
  const size_t idx = (size_t)blockIdx.x * 256 + threadIdx.x;
  const size_t i = idx / kD;
  float m = ml[i * 2];
#pragma unroll
  for (int sp = 1; sp < SPLITf; ++sp)
    m = fmaxf(m, ml[((size_t)sp * kN + i) * 2]);
  float den = 0.f, acc = 0.f;
#pragma unroll
  for (int sp = 0; sp < SPLITf; ++sp) {
    const float e = __expf(ml[((size_t)sp * kN + i) * 2] - m);
    den += e * ml[((size_t)sp * kN + i) * 2 + 1];
    acc += e * Opart[(size_t)sp * kND + idx];
  }
  O[idx] = acc / den;
}

// ---------------------------------------------------------------------------
// Layer-2: exact matvec formulation (no full GEMMs).
// ---------------------------------------------------------------------------
__global__ __launch_bounds__(64) void qrow_kernel(
    const float* __restrict__ h1, const float* __restrict__ Wq,
    float* __restrict__ q2)
{
  const int j = blockIdx.x;
  const int lane = threadIdx.x;
  const float* hr = h1 + (size_t)(kN - 1) * kD;
  float acc = 0.f;
  for (int d = lane; d < kD; d += 64) acc += hr[d] * Wq[(size_t)j * kD + d];
#pragma unroll
  for (int off = 32; off > 0; off >>= 1) acc += __shfl_xor(acc, off, 64);
  if (lane == 0) q2[j] = acc;
}

__global__ __launch_bounds__(384) void u_kernel(
    const float* __restrict__ Wk, const float* __restrict__ q2,
    float* __restrict__ u)
{
  __shared__ float qs[kD];
  const int d = threadIdx.x;
  qs[d] = q2[d];
  __syncthreads();
  float acc = 0.f;
  for (int k = 0; k < kD; ++k) acc += Wk[(size_t)k * kD + d] * qs[k];
  u[d] = acc;
}

__global__ __launch_bounds__(256) void logits_kernel(
    const float* __restrict__ h1, const float* __restrict__ u,
    float* __restrict__ lg)
{
  const int wave = threadIdx.x >> 6;
  const int lane = threadIdx.x & 63;
  const int j = blockIdx.x * 4 + wave;
  float acc = 0.f;
#pragma unroll
  for (int t = 0; t < kD / 64; ++t) {
    const int d = lane + t * 64;
    acc += h1[(size_t)j * kD + d] * u[d];
  }
#pragma unroll
  for (int off = 32; off > 0; off >>= 1) acc += __shfl_xor(acc, off, 64);
  if (lane == 0) lg[j] = acc;
}

__global__ __launch_bounds__(1024) void smax_kernel(
    const float* __restrict__ lg, float* __restrict__ wgt)
{
  __shared__ float red[16];
  const int t = threadIdx.x;
  const int wave = t >> 6;
  const int lane = t & 63;
  float v[8];
  float mx = -INFINITY;
#pragma unroll
  for (int s = 0; s < 8; ++s) {
    v[s] = lg[t + 1024 * s];
    mx = fmaxf(mx, v[s]);
  }
#pragma unroll
  for (int off = 32; off > 0; off >>= 1) mx = fmaxf(mx, __shfl_xor(mx, off, 64));
  if (lane == 0) red[wave] = mx;
  __syncthreads();
  if (t == 0) {
    float m = red[0];
    for (int i = 1; i < 16; ++i) m = fmaxf(m, red[i]);
    red[0] = m;
  }
  __syncthreads();
  const float m = red[0];
  __syncthreads();
  float sum = 0.f;
#pragma unroll
  for (int s = 0; s < 8; ++s) {
    v[s] = expf(v[s] - m);
    sum += v[s];
  }
#pragma unroll
  for (int off = 32; off > 0; off >>= 1) sum += __shfl_xor(sum, off, 64);
  if (lane == 0) red[wave] = sum;
  __syncthreads();
  if (t == 0) {
    float S = 0.f;
    for (int i = 0; i < 16; ++i) S += red[i];
    red[0] = S;
  }
  __syncthreads();
  const float invS = 1.0f / red[0];
#pragma unroll
  for (int s = 0; s < 8; ++s) wgt[t + 1024 * s] = v[s] * invS;
}

// part[b][d] = sum_{j in block b's 256 rows} wgt[j] * h1[j][d]
__global__ __launch_bounds__(384) void wsum_kernel(
    const float* __restrict__ wgt, const float* __restrict__ h1,
    float* __restrict__ part)
{
  __shared__ float wl[256];
  const int b = blockIdx.x;
  const int t = threadIdx.x;
  if (t < 256) wl[t] = wgt[b * 256 + t];
  __syncthreads();
  const float* Hp = h1 + (size_t)b * 256 * kD;
  float acc = 0.f;
  for (int j = 0; j < 256; ++j) acc += wl[j] * Hp[(size_t)j * kD + t];
  part[b * kD + t] = acc;
}

__global__ __launch_bounds__(384) void final2_kernel(
    const float* __restrict__ part, const float* __restrict__ Wv,
    const float* __restrict__ ffws, float* __restrict__ out)
{
  __shared__ float zs[kD];
  __shared__ float red[6];
  const int t = threadIdx.x;
  const int wave = t >> 6;
  const int lane = t & 63;
  float z = 0.f;
#pragma unroll
  for (int b = 0; b < 32; ++b) z += part[b * kD + t];
  zs[t] = z;
  __syncthreads();
  float zv = 0.f;
  for (int k = 0; k < kD; ++k) zv += Wv[(size_t)t * kD + k] * zs[k];
  float val = zv * ffws[t];
#pragma unroll
  for (int off = 32; off > 0; off >>= 1) val += __shfl_xor(val, off, 64);
  if (lane == 0) red[wave] = val;
  __syncthreads();
  if (t == 0) {
    float s = red[0];
    for (int i = 1; i < 6; ++i) s += red[i];
    out[0] = 1.0f / (1.0f + expf(-s));
  }
}

// ---------------------------------------------------------------------------
extern "C" void kernel_launch(void* const* d_in, const int* in_sizes, int n_in,
                              void* d_out, int out_size, void* d_ws, size_t ws_size,
                              hipStream_t stream) {
  const float* x    = (const float*)d_in[0];
  const float* Wq   = (const float*)d_in[1];
  const float* Wk   = (const float*)d_in[2];
  const float* Wv   = (const float*)d_in[3];
  const float* ffws = (const float*)d_in[4];
  float* out = (float*)d_out;
  char* wsb = (char*)d_ws;

  ushort* Qh  = (ushort*)wsb;
  ushort* Kh  = Qh + kND;
  ushort* Kl  = Kh + kND;
  ushort* VTh = Kl + kND;
  const size_t bfQKV = 4 * (size_t)kND * 2;
  float* Opart = (float*)(wsb + bfQKV);            // [4][kND]
  float* ml    = Opart + (size_t)SPLITf * kND;     // [4][kN][2]
  float* h1    = ml + (size_t)SPLITf * kN * 2;
  float* q2    = h1 + (size_t)kND;
  float* u     = q2 + kD;
  float* lg    = u + kD;
  float* wgt   = lg + kN;
  float* part  = wgt + kN;

  // fused layer-1 projections -> bf16 operands (Q hi; K hi/lo; V^T hi)
  proj_fused<<<dim3(kN / 64, kD / 64), 256, 0, stream>>>(
      x, Wq, Wk, Wv, Qh, Kh, Kl, VTh);
  // layer-1 attention
  flash_mfma<<<dim3(SPLITf, kN / 128), 512, 0, stream>>>(
      Qh, Kh, Kl, VTh, Opart, ml);
  merge_kernel<<<(kN * kD) / 256, 256, 0, stream>>>(Opart, ml, h1);
  // layer-2 (exact matvec chain)
  qrow_kernel<<<kD, 64, 0, stream>>>(h1, Wq, q2);
  u_kernel<<<1, 384, 0, stream>>>(Wk, q2, u);
  logits_kernel<<<kN / 4, 256, 0, stream>>>(h1, u, lg);
  smax_kernel<<<1, 1024, 0, stream>>>(lg, wgt);
  wsum_kernel<<<32, 384, 0, stream>>>(wgt, h1, part);
  final2_kernel<<<1, 384, 0, stream>>>(part, Wv, ffws, out);
}

// Round 10
// 286.171 us; speedup vs baseline: 3.1239x; 1.2679x over previous
//
#include <hip/hip_runtime.h>
#include <hip/hip_bf16.h>
#include <math.h>

static constexpr int kN = 8192;
static constexpr int kD = 384;
static constexpr int kND = kN * kD;

typedef __attribute__((ext_vector_type(8))) short short8;
typedef __attribute__((ext_vector_type(4))) float f32x4;

// ---- bf16 helpers (bit-exact RNE) ----
__device__ __forceinline__ ushort f2bf(float f) {
  union { float f; unsigned int i; } cv; cv.f = f;
  unsigned int lsb = (cv.i >> 16) & 1u;
  unsigned int r = cv.i + 0x7fffu + lsb;
  return (ushort)(r >> 16);
}
__device__ __forceinline__ float bf2f(ushort u) {
  union { unsigned int i; float f; } cv; cv.i = ((unsigned int)u) << 16;
  return cv.f;
}
__device__ __forceinline__ f32x4 mfma_bf16(short8 a, short8 b, f32x4 c) {
  return __builtin_amdgcn_mfma_f32_16x16x32_bf16(a, b, c, 0, 0, 0);
}
// LDS-only barrier: drains LDS ops for cross-wave visibility; in-flight
// global loads survive (no vmcnt(0) drain).
__device__ __forceinline__ void bar_lds() {
  asm volatile("s_waitcnt lgkmcnt(0)" ::: "memory");
  __builtin_amdgcn_s_barrier();
}

// ---------------------------------------------------------------------------
// MFMA projection: Y = x @ W^T for W in {Wq, Wk, Wv} (blockIdx.z selects).
// 3-term compensated bf16 (err ~2^-16 vs fp32).  Outputs bf16-hi:
//   z=0 -> Qh row-major, z=1 -> Kh row-major, z=2 -> VTh transposed [D][N].
// Block: 512 thr (8 waves), output tile 128 rows x 96 cols, d-loop 12x32.
// Wave w owns rows [16w,16w+16); 6 col-tiles of 16.
// MFMA layout cloned from flash (C-row <-> A(x)-rows, C-col <-> B(W)-rows):
//   out row = i0+16w+4*hi4+r, col = j0+16ct+l15.
// LDS: XH/XL 128x32, WH/WL 96x32 bf16 = 28.7 KB.
// ---------------------------------------------------------------------------
__global__ __launch_bounds__(512) void proj_mfma(
    const float* __restrict__ x, const float* __restrict__ Wq,
    const float* __restrict__ Wk, const float* __restrict__ Wv,
    ushort* __restrict__ Qh, ushort* __restrict__ Kh,
    ushort* __restrict__ VTh)
{
  __shared__ ushort XH[128 * 32], XL[128 * 32];
  __shared__ ushort WH[96 * 32], WL[96 * 32];

  const int tid = threadIdx.x;
  const int w = tid >> 6;
  const int lane = tid & 63;
  const int l15 = lane & 15;
  const int hi4 = lane >> 4;
  const int i0 = blockIdx.x * 128;
  const int j0 = blockIdx.y * 96;
  const int m = blockIdx.z;
  const float* W = (m == 0) ? Wq : (m == 1) ? Wk : Wv;

  const f32x4 zf = {0.f, 0.f, 0.f, 0.f};
  f32x4 acc[6];
#pragma unroll
  for (int ct = 0; ct < 6; ++ct) acc[ct] = zf;

  const int xrow = tid >> 2;
  const int xc8 = (tid & 3) * 8;

  for (int dc = 0; dc < 12; ++dc) {
    const int d0 = dc * 32;
    // ---- stage x tile 128x32 as bf16 hi/lo ----
    {
      const float* src = x + (size_t)(i0 + xrow) * kD + d0 + xc8;
      const float4 v0 = *reinterpret_cast<const float4*>(src);
      const float4 v1 = *reinterpret_cast<const float4*>(src + 4);
      const float vs[8] = {v0.x, v0.y, v0.z, v0.w, v1.x, v1.y, v1.z, v1.w};
      ushort hh[8], ll[8];
#pragma unroll
      for (int j = 0; j < 8; ++j) {
        const ushort h = f2bf(vs[j]);
        hh[j] = h;
        ll[j] = f2bf(vs[j] - bf2f(h));
      }
      *reinterpret_cast<uint4*>(&XH[xrow * 32 + xc8]) =
          *reinterpret_cast<const uint4*>(hh);
      *reinterpret_cast<uint4*>(&XL[xrow * 32 + xc8]) =
          *reinterpret_cast<const uint4*>(ll);
    }
    // ---- stage W tile 96x32 as bf16 hi/lo (threads 0..383) ----
    if (tid < 384) {
      const float* src = W + (size_t)(j0 + xrow) * kD + d0 + xc8;
      const float4 v0 = *reinterpret_cast<const float4*>(src);
      const float4 v1 = *reinterpret_cast<const float4*>(src + 4);
      const float vs[8] = {v0.x, v0.y, v0.z, v0.w, v1.x, v1.y, v1.z, v1.w};
      ushort hh[8], ll[8];
#pragma unroll
      for (int j = 0; j < 8; ++j) {
        const ushort h = f2bf(vs[j]);
        hh[j] = h;
        ll[j] = f2bf(vs[j] - bf2f(h));
      }
      *reinterpret_cast<uint4*>(&WH[xrow * 32 + xc8]) =
          *reinterpret_cast<const uint4*>(hh);
      *reinterpret_cast<uint4*>(&WL[xrow * 32 + xc8]) =
          *reinterpret_cast<const uint4*>(ll);
    }
    __syncthreads();
    // ---- compute: a = x rows (16w+l15), b = W rows (16ct+l15) ----
    const short8 xa = *reinterpret_cast<const short8*>(
        &XH[(16 * w + l15) * 32 + 8 * hi4]);
    const short8 xb = *reinterpret_cast<const short8*>(
        &XL[(16 * w + l15) * 32 + 8 * hi4]);
#pragma unroll
    for (int ct = 0; ct < 6; ++ct) {
      const short8 wh = *reinterpret_cast<const short8*>(
          &WH[(16 * ct + l15) * 32 + 8 * hi4]);
      const short8 wl = *reinterpret_cast<const short8*>(
          &WL[(16 * ct + l15) * 32 + 8 * hi4]);
      acc[ct] = mfma_bf16(xa, wh, acc[ct]);
      acc[ct] = mfma_bf16(xa, wl, acc[ct]);
      acc[ct] = mfma_bf16(xb, wh, acc[ct]);
    }
    __syncthreads();
  }

  // ---- write out ----
  if (m < 2) {
    ushort* Y = (m == 0) ? Qh : Kh;
#pragma unroll
    for (int ct = 0; ct < 6; ++ct)
#pragma unroll
      for (int r = 0; r < 4; ++r)
        Y[(size_t)(i0 + 16 * w + 4 * hi4 + r) * kD + j0 + 16 * ct + l15] =
            f2bf(acc[ct][r]);
  } else {
#pragma unroll
    for (int ct = 0; ct < 6; ++ct) {
      ushort4 h;
      ushort* hp = &h.x;
#pragma unroll
      for (int r = 0; r < 4; ++r) hp[r] = f2bf(acc[ct][r]);
      *reinterpret_cast<ushort4*>(
          &VTh[(size_t)(j0 + 16 * ct + l15) * kN + i0 + 16 * w + 4 * hi4]) = h;
    }
  }
}

// ---------------------------------------------------------------------------
// MFMA flash attention v10: BM=128, 512 threads (8 waves), SPLIT=4
// -> grid (4,64)=256 blocks, 1 block/CU.  Pure-bf16 S = kh*qh (K-lo dropped:
// K traffic halves; S error ~2^-8 vs layer-2 gaps ~1e4 + saturated sigmoid).
// S^T = mfma(K,Q): wave w owns keys [16w,16w+16), all 128 q-rows (qt=0..7).
// K batch-loaded (12 frags, one wait). PV: V-frags batched from global VT
// (wave w owns d-cols [48w,48w+48)), P hi in LDS.
// LDS: Qh 100K | P 34.8K | MLB 8K = 143K.
// ---------------------------------------------------------------------------
static constexpr int SPLITf = 4;
static constexpr int KEYSf = kN / SPLITf;   // 2048
static constexpr int NTIL = KEYSf / 128;    // 16

static constexpr int OFF_QH = 0;        // ushort offsets into LDSU
static constexpr int OFF_P  = 50176;    // 128*392

__global__ __launch_bounds__(512, 2) void flash_mfma(
    const ushort* __restrict__ Qh,
    const ushort* __restrict__ Kh,
    const ushort* __restrict__ VTh,
    float* __restrict__ Opart, float* __restrict__ ml)
{
  __shared__ ushort LDSU[67584];   // 135168 B (Qh 128x392 | P 128x136)
  __shared__ float MLB[2048];      // m: [0,1024), l: [1024,2048)

  const int tid = threadIdx.x;
  const int w = tid >> 6;
  const int lane = tid & 63;
  const int l15 = lane & 15;
  const int hi4 = lane >> 4;
  const int sp = blockIdx.x;
  const int i0 = blockIdx.y * 128;
  const int kg0 = sp * KEYSf;

  // ---- stage Q-hi once: 128 rows, stride 392 ushorts ----
  {
    const int row = tid >> 2;            // 0..127
    const int sg = (tid & 3) * 96;       // 96 ushorts = 12 x uint4
    const ushort* sh = Qh + (size_t)(i0 + row) * kD + sg;
    ushort* dh = LDSU + OFF_QH + row * 392 + sg;
#pragma unroll
    for (int u = 0; u < 12; ++u)
      *reinterpret_cast<uint4*>(dh + 8 * u) =
          *reinterpret_cast<const uint4*>(sh + 8 * u);
  }

  const f32x4 zf = {0.f, 0.f, 0.f, 0.f};
  f32x4 o[8][3];
#pragma unroll
  for (int qt = 0; qt < 8; ++qt)
#pragma unroll
    for (int c = 0; c < 3; ++c) o[qt][c] = zf;
  float m_run[8], l_run[8];
#pragma unroll
  for (int qt = 0; qt < 8; ++qt) { m_run[qt] = -INFINITY; l_run[qt] = 0.f; }

  __syncthreads();   // Q staged

  for (int kb = 0; kb < NTIL; ++kb) {
    const int kg = kg0 + kb * 128;

    // ---- S phase: K hi batch-loaded (12 frags), Q hi from LDS ----
    f32x4 sacc[8];
#pragma unroll
    for (int qt = 0; qt < 8; ++qt) sacc[qt] = zf;
    const size_t kbase = (size_t)(kg + 16 * w + l15) * kD + 8 * hi4;
    short8 ka[12];
#pragma unroll
    for (int ks = 0; ks < 12; ++ks)
      ka[ks] = *reinterpret_cast<const short8*>(Kh + kbase + 32 * ks);
    __builtin_amdgcn_sched_barrier(0);   // keep loads batched above MFMAs
#pragma unroll
    for (int ks = 0; ks < 12; ++ks) {
      const int d0 = 32 * ks;
#pragma unroll
      for (int qt = 0; qt < 8; ++qt) {
        const short8 qh = *reinterpret_cast<const short8*>(
            LDSU + OFF_QH + (16 * qt + l15) * 392 + d0 + 8 * hi4);
        sacc[qt] = mfma_bf16(ka[ks], qh, sacc[qt]);
      }
    }

    // ---- online softmax (8 q-tiles) ----
    float mt8[8];
#pragma unroll
    for (int qt = 0; qt < 8; ++qt) {
      float mt = fmaxf(fmaxf(sacc[qt][0], sacc[qt][1]),
                       fmaxf(sacc[qt][2], sacc[qt][3]));
      mt = fmaxf(mt, __shfl_xor(mt, 16, 64));
      mt = fmaxf(mt, __shfl_xor(mt, 32, 64));
      mt8[qt] = mt;
    }
    if (lane < 16) {
#pragma unroll
      for (int qt = 0; qt < 8; ++qt) MLB[w * 128 + qt * 16 + l15] = mt8[qt];
    }
    bar_lds();  // B1
    float sc[8];
#pragma unroll
    for (int qt = 0; qt < 8; ++qt) {
      float Mt = MLB[qt * 16 + l15];
#pragma unroll
      for (int w2 = 1; w2 < 8; ++w2)
        Mt = fmaxf(Mt, MLB[w2 * 128 + qt * 16 + l15]);
      const float mnew = fmaxf(m_run[qt], Mt);
      sc[qt] = __expf(m_run[qt] - mnew);
      m_run[qt] = mnew;
      const float p0 = __expf(sacc[qt][0] - mnew);
      const float p1 = __expf(sacc[qt][1] - mnew);
      const float p2 = __expf(sacc[qt][2] - mnew);
      const float p3 = __expf(sacc[qt][3] - mnew);
      float ls = (p0 + p1) + (p2 + p3);
      ls += __shfl_xor(ls, 16, 64);
      ls += __shfl_xor(ls, 32, 64);
      if (lane < 16) MLB[1024 + w * 128 + qt * 16 + l15] = ls;
      // pack P -> bf16 hi, one b64 write
      uint2 HH;
      HH.x = (unsigned int)f2bf(p0) | ((unsigned int)f2bf(p1) << 16);
      HH.y = (unsigned int)f2bf(p2) | ((unsigned int)f2bf(p3) << 16);
      const int pi = (16 * qt + l15) * 136 + 16 * w + 4 * hi4;
      *reinterpret_cast<uint2*>(LDSU + OFF_P + pi) = HH;
      // rescale O (row of o = qrow 16qt+4*hi4+r)
#pragma unroll
      for (int r = 0; r < 4; ++r) {
        const float scr_ = __shfl(sc[qt], 4 * hi4 + r, 64);
#pragma unroll
        for (int c = 0; c < 3; ++c) o[qt][c][r] *= scr_;
      }
    }
    bar_lds();  // B2: P + mlb_l ready
#pragma unroll
    for (int qt = 0; qt < 8; ++qt) {
      float acc = MLB[1024 + qt * 16 + l15];
#pragma unroll
      for (int w2 = 1; w2 < 8; ++w2)
        acc += MLB[1024 + w2 * 128 + qt * 16 + l15];
      l_run[qt] = l_run[qt] * sc[qt] + acc;
    }

    // ---- PV: batch-issue 12 V-frag loads, then 96 MFMAs ----
    short8 vv[12];
#pragma unroll
    for (int c = 0; c < 3; ++c)
#pragma unroll
      for (int kv = 0; kv < 4; ++kv)
        vv[c * 4 + kv] = *reinterpret_cast<const short8*>(
            VTh + (size_t)(48 * w + 16 * c + l15) * kN + kg + 32 * kv + 8 * hi4);
    __builtin_amdgcn_sched_barrier(0);
#pragma unroll
    for (int kv = 0; kv < 4; ++kv) {
      short8 pf[8];
#pragma unroll
      for (int qt = 0; qt < 8; ++qt)
        pf[qt] = *reinterpret_cast<const short8*>(
            LDSU + OFF_P + (16 * qt + l15) * 136 + 32 * kv + 8 * hi4);
#pragma unroll
      for (int c = 0; c < 3; ++c) {
#pragma unroll
        for (int qt = 0; qt < 8; ++qt)
          o[qt][c] = mfma_bf16(pf[qt], vv[c * 4 + kv], o[qt][c]);
      }
    }
  }

  // ---- write unnormalized partials + (m,l); waves own disjoint d-cols ----
#pragma unroll
  for (int qt = 0; qt < 8; ++qt)
#pragma unroll
    for (int c = 0; c < 3; ++c)
#pragma unroll
      for (int r = 0; r < 4; ++r)
        Opart[(size_t)sp * kND + (i0 + 16 * qt + 4 * hi4 + r) * kD +
              48 * w + 16 * c + l15] = o[qt][c][r];
  if (w == 0 && lane < 16) {
#pragma unroll
    for (int qt = 0; qt < 8; ++qt) {
      const int mi = (sp * kN + i0 + 16 * qt + l15) * 2;
      ml[mi] = m_run[qt];
      ml[mi + 1] = l_run[qt];
    }
  }
}

// ---------------------------------------------------------------------------
// Merge 4 key-split partials (unnormalized + per-split (m,l))
// ---------------------------------------------------------------------------
__global__ __launch_bounds__(256) void merge_kernel(
    const float* __restrict__ Opart, const float* __restrict__ ml,
    float* __restrict__ O)
{
  const size_t idx = (size_t)blockIdx.x * 256 + threadIdx.x;
  const size_t i = idx / kD;
  float m = ml[i * 2];
#pragma unroll
  for (int sp = 1; sp < SPLITf; ++sp)
    m = fmaxf(m, ml[((size_t)sp * kN + i) * 2]);
  float den = 0.f, acc = 0.f;
#pragma unroll
  for (int sp = 0; sp < SPLITf; ++sp) {
    const float e = __expf(ml[((size_t)sp * kN + i) * 2] - m);
    den += e * ml[((size_t)sp * kN + i) * 2 + 1];
    acc += e * Opart[(size_t)sp * kND + idx];
  }
  O[idx] = acc / den;
}

// ---------------------------------------------------------------------------
// Layer-2: exact matvec formulation (no full GEMMs).
// ---------------------------------------------------------------------------
__global__ __launch_bounds__(64) void qrow_kernel(
    const float* __restrict__ h1, const float* __restrict__ Wq,
    float* __restrict__ q2)
{
  const int j = blockIdx.x;
  const int lane = threadIdx.x;
  const float* hr = h1 + (size_t)(kN - 1) * kD;
  float acc = 0.f;
  for (int d = lane; d < kD; d += 64) acc += hr[d] * Wq[(size_t)j * kD + d];
#pragma unroll
  for (int off = 32; off > 0; off >>= 1) acc += __shfl_xor(acc, off, 64);
  if (lane == 0) q2[j] = acc;
}

__global__ __launch_bounds__(384) void u_kernel(
    const float* __restrict__ Wk, const float* __restrict__ q2,
    float* __restrict__ u)
{
  __shared__ float qs[kD];
  const int d = threadIdx.x;
  qs[d] = q2[d];
  __syncthreads();
  float acc = 0.f;
  for (int k = 0; k < kD; ++k) acc += Wk[(size_t)k * kD + d] * qs[k];
  u[d] = acc;
}

__global__ __launch_bounds__(256) void logits_kernel(
    const float* __restrict__ h1, const float* __restrict__ u,
    float* __restrict__ lg)
{
  const int wave = threadIdx.x >> 6;
  const int lane = threadIdx.x & 63;
  const int j = blockIdx.x * 4 + wave;
  float acc = 0.f;
#pragma unroll
  for (int t = 0; t < kD / 64; ++t) {
    const int d = lane + t * 64;
    acc += h1[(size_t)j * kD + d] * u[d];
  }
#pragma unroll
  for (int off = 32; off > 0; off >>= 1) acc += __shfl_xor(acc, off, 64);
  if (lane == 0) lg[j] = acc;
}

__global__ __launch_bounds__(1024) void smax_kernel(
    const float* __restrict__ lg, float* __restrict__ wgt)
{
  __shared__ float red[16];
  const int t = threadIdx.x;
  const int wave = t >> 6;
  const int lane = t & 63;
  float v[8];
  float mx = -INFINITY;
#pragma unroll
  for (int s = 0; s < 8; ++s) {
    v[s] = lg[t + 1024 * s];
    mx = fmaxf(mx, v[s]);
  }
#pragma unroll
  for (int off = 32; off > 0; off >>= 1) mx = fmaxf(mx, __shfl_xor(mx, off, 64));
  if (lane == 0) red[wave] = mx;
  __syncthreads();
  if (t == 0) {
    float m = red[0];
    for (int i = 1; i < 16; ++i) m = fmaxf(m, red[i]);
    red[0] = m;
  }
  __syncthreads();
  const float m = red[0];
  __syncthreads();
  float sum = 0.f;
#pragma unroll
  for (int s = 0; s < 8; ++s) {
    v[s] = expf(v[s] - m);
    sum += v[s];
  }
#pragma unroll
  for (int off = 32; off > 0; off >>= 1) sum += __shfl_xor(sum, off, 64);
  if (lane == 0) red[wave] = sum;
  __syncthreads();
  if (t == 0) {
    float S = 0.f;
    for (int i = 0; i < 16; ++i) S += red[i];
    red[0] = S;
  }
  __syncthreads();
  const float invS = 1.0f / red[0];
#pragma unroll
  for (int s = 0; s < 8; ++s) wgt[t + 1024 * s] = v[s] * invS;
}

// part[b][d] = sum_{j in block b's 256 rows} wgt[j] * h1[j][d]
__global__ __launch_bounds__(384) void wsum_kernel(
    const float* __restrict__ wgt, const float* __restrict__ h1,
    float* __restrict__ part)
{
  __shared__ float wl[256];
  const int b = blockIdx.x;
  const int t = threadIdx.x;
  if (t < 256) wl[t] = wgt[b * 256 + t];
  __syncthreads();
  const float* Hp = h1 + (size_t)b * 256 * kD;
  float acc = 0.f;
  for (int j = 0; j < 256; ++j) acc += wl[j] * Hp[(size_t)j * kD + t];
  part[b * kD + t] = acc;
}

__global__ __launch_bounds__(384) void final2_kernel(
    const float* __restrict__ part, const float* __restrict__ Wv,
    const float* __restrict__ ffws, float* __restrict__ out)
{
  __shared__ float zs[kD];
  __shared__ float red[6];
  const int t = threadIdx.x;
  const int wave = t >> 6;
  const int lane = t & 63;
  float z = 0.f;
#pragma unroll
  for (int b = 0; b < 32; ++b) z += part[b * kD + t];
  zs[t] = z;
  __syncthreads();
  float zv = 0.f;
  for (int k = 0; k < kD; ++k) zv += Wv[(size_t)t * kD + k] * zs[k];
  float val = zv * ffws[t];
#pragma unroll
  for (int off = 32; off > 0; off >>= 1) val += __shfl_xor(val, off, 64);
  if (lane == 0) red[wave] = val;
  __syncthreads();
  if (t == 0) {
    float s = red[0];
    for (int i = 1; i < 6; ++i) s += red[i];
    out[0] = 1.0f / (1.0f + expf(-s));
  }
}

// ---------------------------------------------------------------------------
extern "C" void kernel_launch(void* const* d_in, const int* in_sizes, int n_in,
                              void* d_out, int out_size, void* d_ws, size_t ws_size,
                              hipStream_t stream) {
  const float* x    = (const float*)d_in[0];
  const float* Wq   = (const float*)d_in[1];
  const float* Wk   = (const float*)d_in[2];
  const float* Wv   = (const float*)d_in[3];
  const float* ffws = (const float*)d_in[4];
  float* out = (float*)d_out;
  char* wsb = (char*)d_ws;

  ushort* Qh  = (ushort*)wsb;
  ushort* Kh  = Qh + kND;
  ushort* VTh = Kh + kND;
  const size_t bfQKV = 3 * (size_t)kND * 2;
  float* Opart = (float*)(wsb + bfQKV);            // [4][kND]
  float* ml    = Opart + (size_t)SPLITf * kND;     // [4][kN][2]
  float* h1    = ml + (size_t)SPLITf * kN * 2;
  float* q2    = h1 + (size_t)kND;
  float* u     = q2 + kD;
  float* lg    = u + kD;
  float* wgt   = lg + kN;
  float* part  = wgt + kN;

  // layer-1 projections via MFMA (Q hi; K hi; V^T hi)
  proj_mfma<<<dim3(kN / 128, kD / 96, 3), 512, 0, stream>>>(
      x, Wq, Wk, Wv, Qh, Kh, VTh);
  // layer-1 attention
  flash_mfma<<<dim3(SPLITf, kN / 128), 512, 0, stream>>>(
      Qh, Kh, VTh, Opart, ml);
  merge_kernel<<<(kN * kD) / 256, 256, 0, stream>>>(Opart, ml, h1);
  // layer-2 (exact matvec chain)
  qrow_kernel<<<kD, 64, 0, stream>>>(h1, Wq, q2);
  u_kernel<<<1, 384, 0, stream>>>(Wk, q2, u);
  logits_kernel<<<kN / 4, 256, 0, stream>>>(h1, u, lg);
  smax_kernel<<<1, 1024, 0, stream>>>(lg, wgt);
  wsum_kernel<<<32, 384, 0, stream>>>(wgt, h1, part);
  final2_kernel<<<1, 384, 0, stream>>>(part, Wv, ffws, out);
}

// Round 11
// 284.750 us; speedup vs baseline: 3.1394x; 1.0050x over previous
//
#include <hip/hip_runtime.h>
#include <hip/hip_bf16.h>
#include <math.h>

static constexpr int kN = 8192;
static constexpr int kD = 384;
static constexpr int kND = kN * kD;

typedef __attribute__((ext_vector_type(8))) short short8;
typedef __attribute__((ext_vector_type(4))) float f32x4;

// ---- bf16 helpers (bit-exact RNE) ----
__device__ __forceinline__ ushort f2bf(float f) {
  union { float f; unsigned int i; } cv; cv.f = f;
  unsigned int lsb = (cv.i >> 16) & 1u;
  unsigned int r = cv.i + 0x7fffu + lsb;
  return (ushort)(r >> 16);
}
__device__ __forceinline__ float bf2f(ushort u) {
  union { unsigned int i; float f; } cv; cv.i = ((unsigned int)u) << 16;
  return cv.f;
}
__device__ __forceinline__ f32x4 mfma_bf16(short8 a, short8 b, f32x4 c) {
  return __builtin_amdgcn_mfma_f32_16x16x32_bf16(a, b, c, 0, 0, 0);
}
// LDS-only barrier: drains LDS ops for cross-wave visibility; in-flight
// global loads survive (no vmcnt(0) drain).
__device__ __forceinline__ void bar_lds() {
  asm volatile("s_waitcnt lgkmcnt(0)" ::: "memory");
  __builtin_amdgcn_s_barrier();
}

// ---------------------------------------------------------------------------
// Fused MFMA projection (single pass): stage x tile ONCE, compute all of
//   Qh = bf16(x@Wq^T), Kh = bf16(x@Wk^T)  (row-major [N][D])
//   VTh = bf16((x@Wv^T)^T)                 ([D][N])
// 3-term compensated bf16 (err ~2^-16 vs fp32).
// Block: 512 thr (8 waves), tile 128 rows x 96 cols, d-loop 12x32.
// Wave w owns rows [16w,16w+16); per d-iter: 3 mats x 6 ct x 3 terms = 54 MFMA.
// LDS: X hi/lo 128x32 (16K) + W hi/lo 3x96x32 (36.9K) = 52.9 KB.
// ---------------------------------------------------------------------------
__global__ __launch_bounds__(512) void proj_mfma(
    const float* __restrict__ x, const float* __restrict__ Wq,
    const float* __restrict__ Wk, const float* __restrict__ Wv,
    ushort* __restrict__ Qh, ushort* __restrict__ Kh,
    ushort* __restrict__ VTh)
{
  __shared__ ushort XH[128 * 32], XL[128 * 32];
  __shared__ ushort WH[3][96 * 32], WL[3][96 * 32];

  const int tid = threadIdx.x;
  const int w = tid >> 6;
  const int lane = tid & 63;
  const int l15 = lane & 15;
  const int hi4 = lane >> 4;
  const int i0 = blockIdx.x * 128;
  const int j0 = blockIdx.y * 96;
  const float* Wm[3] = {Wq, Wk, Wv};

  const f32x4 zf = {0.f, 0.f, 0.f, 0.f};
  f32x4 acc[3][6];
#pragma unroll
  for (int m = 0; m < 3; ++m)
#pragma unroll
    for (int ct = 0; ct < 6; ++ct) acc[m][ct] = zf;

  const int xrow = tid >> 2;
  const int xc8 = (tid & 3) * 8;

  for (int dc = 0; dc < 12; ++dc) {
    const int d0 = dc * 32;
    // ---- stage x tile 128x32 as bf16 hi/lo ----
    {
      const float* src = x + (size_t)(i0 + xrow) * kD + d0 + xc8;
      const float4 v0 = *reinterpret_cast<const float4*>(src);
      const float4 v1 = *reinterpret_cast<const float4*>(src + 4);
      const float vs[8] = {v0.x, v0.y, v0.z, v0.w, v1.x, v1.y, v1.z, v1.w};
      ushort hh[8], ll[8];
#pragma unroll
      for (int j = 0; j < 8; ++j) {
        const ushort h = f2bf(vs[j]);
        hh[j] = h;
        ll[j] = f2bf(vs[j] - bf2f(h));
      }
      *reinterpret_cast<uint4*>(&XH[xrow * 32 + xc8]) =
          *reinterpret_cast<const uint4*>(hh);
      *reinterpret_cast<uint4*>(&XL[xrow * 32 + xc8]) =
          *reinterpret_cast<const uint4*>(ll);
    }
    // ---- stage 3 W tiles 96x32 as bf16 hi/lo (threads 0..383) ----
    if (tid < 384) {
#pragma unroll
      for (int m = 0; m < 3; ++m) {
        const float* src = Wm[m] + (size_t)(j0 + xrow) * kD + d0 + xc8;
        const float4 v0 = *reinterpret_cast<const float4*>(src);
        const float4 v1 = *reinterpret_cast<const float4*>(src + 4);
        const float vs[8] = {v0.x, v0.y, v0.z, v0.w, v1.x, v1.y, v1.z, v1.w};
        ushort hh[8], ll[8];
#pragma unroll
        for (int j = 0; j < 8; ++j) {
          const ushort h = f2bf(vs[j]);
          hh[j] = h;
          ll[j] = f2bf(vs[j] - bf2f(h));
        }
        *reinterpret_cast<uint4*>(&WH[m][xrow * 32 + xc8]) =
            *reinterpret_cast<const uint4*>(hh);
        *reinterpret_cast<uint4*>(&WL[m][xrow * 32 + xc8]) =
            *reinterpret_cast<const uint4*>(ll);
      }
    }
    __syncthreads();
    // ---- compute: a = x rows (16w+l15), b = W rows (16ct+l15) ----
    const short8 xa = *reinterpret_cast<const short8*>(
        &XH[(16 * w + l15) * 32 + 8 * hi4]);
    const short8 xb = *reinterpret_cast<const short8*>(
        &XL[(16 * w + l15) * 32 + 8 * hi4]);
#pragma unroll
    for (int m = 0; m < 3; ++m) {
#pragma unroll
      for (int ct = 0; ct < 6; ++ct) {
        const short8 wh = *reinterpret_cast<const short8*>(
            &WH[m][(16 * ct + l15) * 32 + 8 * hi4]);
        const short8 wl = *reinterpret_cast<const short8*>(
            &WL[m][(16 * ct + l15) * 32 + 8 * hi4]);
        acc[m][ct] = mfma_bf16(xa, wh, acc[m][ct]);
        acc[m][ct] = mfma_bf16(xa, wl, acc[m][ct]);
        acc[m][ct] = mfma_bf16(xb, wh, acc[m][ct]);
      }
    }
    __syncthreads();
  }

  // ---- write out: Q,K row-major; V transposed ----
#pragma unroll
  for (int ct = 0; ct < 6; ++ct)
#pragma unroll
    for (int r = 0; r < 4; ++r) {
      const size_t oi =
          (size_t)(i0 + 16 * w + 4 * hi4 + r) * kD + j0 + 16 * ct + l15;
      Qh[oi] = f2bf(acc[0][ct][r]);
      Kh[oi] = f2bf(acc[1][ct][r]);
    }
#pragma unroll
  for (int ct = 0; ct < 6; ++ct) {
    ushort4 h;
    ushort* hp = &h.x;
#pragma unroll
    for (int r = 0; r < 4; ++r) hp[r] = f2bf(acc[2][ct][r]);
    *reinterpret_cast<ushort4*>(
        &VTh[(size_t)(j0 + 16 * ct + l15) * kN + i0 + 16 * w + 4 * hi4]) = h;
  }
}

// ---------------------------------------------------------------------------
// MFMA flash attention v11: BM=128, 512 threads (8 waves), SPLIT=4
// -> grid (4,64)=256 blocks, 1 block/CU.  Pure-bf16 S = kh*qh.
// Per tile: [K batch-load, S MFMAs] [B1] [V-EARLY issue (overlaps softmax)]
// [softmax w/ vectorized MLB] [B2] [PV].
// MLB layout [row][8 waves] -> cross-wave reduce = 2 float4 LDS reads.
// Epilogue stores NORMALIZED bf16 partials (halves merge traffic).
// LDS: Qh 100K | P 34.8K | MLB 8K = 143K.
// ---------------------------------------------------------------------------
static constexpr int SPLITf = 4;
static constexpr int KEYSf = kN / SPLITf;   // 2048
static constexpr int NTIL = KEYSf / 128;    // 16

static constexpr int OFF_QH = 0;        // ushort offsets into LDSU
static constexpr int OFF_P  = 50176;    // 128*392

__global__ __launch_bounds__(512, 2) void flash_mfma(
    const ushort* __restrict__ Qh,
    const ushort* __restrict__ Kh,
    const ushort* __restrict__ VTh,
    ushort* __restrict__ Opart, float* __restrict__ ml)
{
  __shared__ ushort LDSU[67584];   // 135168 B (Qh 128x392 | P 128x136)
  __shared__ float MLB[2048];      // m: [(row)*8+w], l: 1024 + same

  const int tid = threadIdx.x;
  const int w = tid >> 6;
  const int lane = tid & 63;
  const int l15 = lane & 15;
  const int hi4 = lane >> 4;
  const int sp = blockIdx.x;
  const int i0 = blockIdx.y * 128;
  const int kg0 = sp * KEYSf;

  // ---- stage Q-hi once: 128 rows, stride 392 ushorts ----
  {
    const int row = tid >> 2;            // 0..127
    const int sg = (tid & 3) * 96;       // 96 ushorts = 12 x uint4
    const ushort* sh = Qh + (size_t)(i0 + row) * kD + sg;
    ushort* dh = LDSU + OFF_QH + row * 392 + sg;
#pragma unroll
    for (int u = 0; u < 12; ++u)
      *reinterpret_cast<uint4*>(dh + 8 * u) =
          *reinterpret_cast<const uint4*>(sh + 8 * u);
  }

  const f32x4 zf = {0.f, 0.f, 0.f, 0.f};
  f32x4 o[8][3];
#pragma unroll
  for (int qt = 0; qt < 8; ++qt)
#pragma unroll
    for (int c = 0; c < 3; ++c) o[qt][c] = zf;
  float m_run[8], l_run[8];
#pragma unroll
  for (int qt = 0; qt < 8; ++qt) { m_run[qt] = -INFINITY; l_run[qt] = 0.f; }

  __syncthreads();   // Q staged

  for (int kb = 0; kb < NTIL; ++kb) {
    const int kg = kg0 + kb * 128;

    // ---- S phase: K hi batch-loaded (12 frags), Q hi from LDS ----
    f32x4 sacc[8];
#pragma unroll
    for (int qt = 0; qt < 8; ++qt) sacc[qt] = zf;
    const size_t kbase = (size_t)(kg + 16 * w + l15) * kD + 8 * hi4;
    short8 ka[12];
#pragma unroll
    for (int ks = 0; ks < 12; ++ks)
      ka[ks] = *reinterpret_cast<const short8*>(Kh + kbase + 32 * ks);
    __builtin_amdgcn_sched_barrier(0);   // keep loads batched above MFMAs
#pragma unroll
    for (int ks = 0; ks < 12; ++ks) {
      const int d0 = 32 * ks;
#pragma unroll
      for (int qt = 0; qt < 8; ++qt) {
        const short8 qh = *reinterpret_cast<const short8*>(
            LDSU + OFF_QH + (16 * qt + l15) * 392 + d0 + 8 * hi4);
        sacc[qt] = mfma_bf16(ka[ks], qh, sacc[qt]);
      }
    }

    // ---- per-wave tile max -> MLB (vector-friendly layout) ----
#pragma unroll
    for (int qt = 0; qt < 8; ++qt) {
      float mt = fmaxf(fmaxf(sacc[qt][0], sacc[qt][1]),
                       fmaxf(sacc[qt][2], sacc[qt][3]));
      mt = fmaxf(mt, __shfl_xor(mt, 16, 64));
      mt = fmaxf(mt, __shfl_xor(mt, 32, 64));
      if (lane < 16) MLB[(qt * 16 + l15) * 8 + w] = mt;
    }
    bar_lds();  // B1: all waves' m published

    // ---- V-EARLY: issue 12 V-frag loads; stream overlaps softmax ----
    short8 vv[12];
#pragma unroll
    for (int c = 0; c < 3; ++c)
#pragma unroll
      for (int kv = 0; kv < 4; ++kv)
        vv[c * 4 + kv] = *reinterpret_cast<const short8*>(
            VTh + (size_t)(48 * w + 16 * c + l15) * kN + kg + 32 * kv + 8 * hi4);
    __builtin_amdgcn_sched_barrier(0);   // pin issue above softmax

    // ---- softmax (vectorized MLB reads) ----
    float sc[8];
#pragma unroll
    for (int qt = 0; qt < 8; ++qt) {
      const float4 ma =
          *reinterpret_cast<const float4*>(&MLB[(qt * 16 + l15) * 8]);
      const float4 mb =
          *reinterpret_cast<const float4*>(&MLB[(qt * 16 + l15) * 8 + 4]);
      const float Mt = fmaxf(fmaxf(fmaxf(ma.x, ma.y), fmaxf(ma.z, ma.w)),
                             fmaxf(fmaxf(mb.x, mb.y), fmaxf(mb.z, mb.w)));
      const float mnew = fmaxf(m_run[qt], Mt);
      sc[qt] = __expf(m_run[qt] - mnew);
      m_run[qt] = mnew;
      const float p0 = __expf(sacc[qt][0] - mnew);
      const float p1 = __expf(sacc[qt][1] - mnew);
      const float p2 = __expf(sacc[qt][2] - mnew);
      const float p3 = __expf(sacc[qt][3] - mnew);
      float ls = (p0 + p1) + (p2 + p3);
      ls += __shfl_xor(ls, 16, 64);
      ls += __shfl_xor(ls, 32, 64);
      if (lane < 16) MLB[1024 + (qt * 16 + l15) * 8 + w] = ls;
      // pack P -> bf16 hi, one b64 write
      uint2 HH;
      HH.x = (unsigned int)f2bf(p0) | ((unsigned int)f2bf(p1) << 16);
      HH.y = (unsigned int)f2bf(p2) | ((unsigned int)f2bf(p3) << 16);
      const int pi = (16 * qt + l15) * 136 + 16 * w + 4 * hi4;
      *reinterpret_cast<uint2*>(LDSU + OFF_P + pi) = HH;
      // rescale O (row of o = qrow 16qt+4*hi4+r)
#pragma unroll
      for (int r = 0; r < 4; ++r) {
        const float scr_ = __shfl(sc[qt], 4 * hi4 + r, 64);
#pragma unroll
        for (int c = 0; c < 3; ++c) o[qt][c][r] *= scr_;
      }
    }
    bar_lds();  // B2: P + l published
#pragma unroll
    for (int qt = 0; qt < 8; ++qt) {
      const float4 la =
          *reinterpret_cast<const float4*>(&MLB[1024 + (qt * 16 + l15) * 8]);
      const float4 lb =
          *reinterpret_cast<const float4*>(&MLB[1024 + (qt * 16 + l15) * 8 + 4]);
      const float ls = ((la.x + la.y) + (la.z + la.w)) +
                       ((lb.x + lb.y) + (lb.z + lb.w));
      l_run[qt] = l_run[qt] * sc[qt] + ls;
    }

    // ---- PV: 96 MFMAs on prefetched vv ----
#pragma unroll
    for (int kv = 0; kv < 4; ++kv) {
      short8 pf[8];
#pragma unroll
      for (int qt = 0; qt < 8; ++qt)
        pf[qt] = *reinterpret_cast<const short8*>(
            LDSU + OFF_P + (16 * qt + l15) * 136 + 32 * kv + 8 * hi4);
#pragma unroll
      for (int c = 0; c < 3; ++c) {
#pragma unroll
        for (int qt = 0; qt < 8; ++qt)
          o[qt][c] = mfma_bf16(pf[qt], vv[c * 4 + kv], o[qt][c]);
      }
    }
  }

  // ---- write NORMALIZED bf16 partials + (m,l) ----
#pragma unroll
  for (int qt = 0; qt < 8; ++qt) {
    const float linv = 1.0f / l_run[qt];
#pragma unroll
    for (int r = 0; r < 4; ++r) {
      const float lr = __shfl(linv, 4 * hi4 + r, 64);
#pragma unroll
      for (int c = 0; c < 3; ++c)
        Opart[(size_t)sp * kND + (i0 + 16 * qt + 4 * hi4 + r) * kD +
              48 * w + 16 * c + l15] = f2bf(o[qt][c][r] * lr);
    }
  }
  if (w == 0 && lane < 16) {
#pragma unroll
    for (int qt = 0; qt < 8; ++qt) {
      const int mi = (sp * kN + i0 + 16 * qt + l15) * 2;
      ml[mi] = m_run[qt];
      ml[mi + 1] = l_run[qt];
    }
  }
}

// ---------------------------------------------------------------------------
// Merge 4 key-split NORMALIZED bf16 partials:
// h1 = sum_sp w_sp*On_sp, w_sp = e^{m_sp-m} l_sp / sum e^{m_sp-m} l_sp
// ---------------------------------------------------------------------------
__global__ __launch_bounds__(256) void merge_kernel(
    const ushort* __restrict__ Opart, const float* __restrict__ ml,
    float* __restrict__ O)
{
  const size_t idx = (size_t)blockIdx.x * 256 + threadIdx.x;
  const size_t i = idx / kD;
  float m = ml[i * 2];
#pragma unroll
  for (int sp = 1; sp < SPLITf; ++sp)
    m = fmaxf(m, ml[((size_t)sp * kN + i) * 2]);
  float den = 0.f, acc = 0.f;
#pragma unroll
  for (int sp = 0; sp < SPLITf; ++sp) {
    const float e = __expf(ml[((size_t)sp * kN + i) * 2] - m) *
                    ml[((size_t)sp * kN + i) * 2 + 1];
    den += e;
    acc += e * bf2f(Opart[(size_t)sp * kND + idx]);
  }
  O[idx] = acc / den;
}

// ---------------------------------------------------------------------------
// Layer-2: exact matvec formulation (no full GEMMs).
// ---------------------------------------------------------------------------
__global__ __launch_bounds__(64) void qrow_kernel(
    const float* __restrict__ h1, const float* __restrict__ Wq,
    float* __restrict__ q2)
{
  const int j = blockIdx.x;
  const int lane = threadIdx.x;
  const float* hr = h1 + (size_t)(kN - 1) * kD;
  float acc = 0.f;
  for (int d = lane; d < kD; d += 64) acc += hr[d] * Wq[(size_t)j * kD + d];
#pragma unroll
  for (int off = 32; off > 0; off >>= 1) acc += __shfl_xor(acc, off, 64);
  if (lane == 0) q2[j] = acc;
}

__global__ __launch_bounds__(384) void u_kernel(
    const float* __restrict__ Wk, const float* __restrict__ q2,
    float* __restrict__ u)
{
  __shared__ float qs[kD];
  const int d = threadIdx.x;
  qs[d] = q2[d];
  __syncthreads();
  float acc = 0.f;
  for (int k = 0; k < kD; ++k) acc += Wk[(size_t)k * kD + d] * qs[k];
  u[d] = acc;
}

__global__ __launch_bounds__(256) void logits_kernel(
    const float* __restrict__ h1, const float* __restrict__ u,
    float* __restrict__ lg)
{
  const int wave = threadIdx.x >> 6;
  const int lane = threadIdx.x & 63;
  const int j = blockIdx.x * 4 + wave;
  float acc = 0.f;
#pragma unroll
  for (int t = 0; t < kD / 64; ++t) {
    const int d = lane + t * 64;
    acc += h1[(size_t)j * kD + d] * u[d];
  }
#pragma unroll
  for (int off = 32; off > 0; off >>= 1) acc += __shfl_xor(acc, off, 64);
  if (lane == 0) lg[j] = acc;
}

__global__ __launch_bounds__(1024) void smax_kernel(
    const float* __restrict__ lg, float* __restrict__ wgt)
{
  __shared__ float red[16];
  const int t = threadIdx.x;
  const int wave = t >> 6;
  const int lane = t & 63;
  float v[8];
  float mx = -INFINITY;
#pragma unroll
  for (int s = 0; s < 8; ++s) {
    v[s] = lg[t + 1024 * s];
    mx = fmaxf(mx, v[s]);
  }
#pragma unroll
  for (int off = 32; off > 0; off >>= 1) mx = fmaxf(mx, __shfl_xor(mx, off, 64));
  if (lane == 0) red[wave] = mx;
  __syncthreads();
  if (t == 0) {
    float m = red[0];
    for (int i = 1; i < 16; ++i) m = fmaxf(m, red[i]);
    red[0] = m;
  }
  __syncthreads();
  const float m = red[0];
  __syncthreads();
  float sum = 0.f;
#pragma unroll
  for (int s = 0; s < 8; ++s) {
    v[s] = expf(v[s] - m);
    sum += v[s];
  }
#pragma unroll
  for (int off = 32; off > 0; off >>= 1) sum += __shfl_xor(sum, off, 64);
  if (lane == 0) red[wave] = sum;
  __syncthreads();
  if (t == 0) {
    float S = 0.f;
    for (int i = 0; i < 16; ++i) S += red[i];
    red[0] = S;
  }
  __syncthreads();
  const float invS = 1.0f / red[0];
#pragma unroll
  for (int s = 0; s < 8; ++s) wgt[t + 1024 * s] = v[s] * invS;
}

// part[b][d] = sum_{j in block b's 256 rows} wgt[j] * h1[j][d]
__global__ __launch_bounds__(384) void wsum_kernel(
    const float* __restrict__ wgt, const float* __restrict__ h1,
    float* __restrict__ part)
{
  __shared__ float wl[256];
  const int b = blockIdx.x;
  const int t = threadIdx.x;
  if (t < 256) wl[t] = wgt[b * 256 + t];
  __syncthreads();
  const float* Hp = h1 + (size_t)b * 256 * kD;
  float acc = 0.f;
  for (int j = 0; j < 256; ++j) acc += wl[j] * Hp[(size_t)j * kD + t];
  part[b * kD + t] = acc;
}

__global__ __launch_bounds__(384) void final2_kernel(
    const float* __restrict__ part, const float* __restrict__ Wv,
    const float* __restrict__ ffws, float* __restrict__ out)
{
  __shared__ float zs[kD];
  __shared__ float red[6];
  const int t = threadIdx.x;
  const int wave = t >> 6;
  const int lane = t & 63;
  float z = 0.f;
#pragma unroll
  for (int b = 0; b < 32; ++b) z += part[b * kD + t];
  zs[t] = z;
  __syncthreads();
  float zv = 0.f;
  for (int k = 0; k < kD; ++k) zv += Wv[(size_t)t * kD + k] * zs[k];
  float val = zv * ffws[t];
#pragma unroll
  for (int off = 32; off > 0; off >>= 1) val += __shfl_xor(val, off, 64);
  if (lane == 0) red[wave] = val;
  __syncthreads();
  if (t == 0) {
    float s = red[0];
    for (int i = 1; i < 6; ++i) s += red[i];
    out[0] = 1.0f / (1.0f + expf(-s));
  }
}

// ---------------------------------------------------------------------------
extern "C" void kernel_launch(void* const* d_in, const int* in_sizes, int n_in,
                              void* d_out, int out_size, void* d_ws, size_t ws_size,
                              hipStream_t stream) {
  const float* x    = (const float*)d_in[0];
  const float* Wq   = (const float*)d_in[1];
  const float* Wk   = (const float*)d_in[2];
  const float* Wv   = (const float*)d_in[3];
  const float* ffws = (const float*)d_in[4];
  float* out = (float*)d_out;
  char* wsb = (char*)d_ws;

  ushort* Qh  = (ushort*)wsb;
  ushort* Kh  = Qh + kND;
  ushort* VTh = Kh + kND;
  ushort* Opart = VTh + kND;                         // bf16 [4][kND]
  float* ml    = (float*)(Opart + (size_t)SPLITf * kND);  // [4][kN][2]
  float* h1    = ml + (size_t)SPLITf * kN * 2;
  float* q2    = h1 + (size_t)kND;
  float* u     = q2 + kD;
  float* lg    = u + kD;
  float* wgt   = lg + kN;
  float* part  = wgt + kN;

  // layer-1 projections (single pass, MFMA)
  proj_mfma<<<dim3(kN / 128, kD / 96), 512, 0, stream>>>(
      x, Wq, Wk, Wv, Qh, Kh, VTh);
  // layer-1 attention
  flash_mfma<<<dim3(SPLITf, kN / 128), 512, 0, stream>>>(
      Qh, Kh, VTh, Opart, ml);
  merge_kernel<<<(kN * kD) / 256, 256, 0, stream>>>(Opart, ml, h1);
  // layer-2 (exact matvec chain)
  qrow_kernel<<<kD, 64, 0, stream>>>(h1, Wq, q2);
  u_kernel<<<1, 384, 0, stream>>>(Wk, q2, u);
  logits_kernel<<<kN / 4, 256, 0, stream>>>(h1, u, lg);
  smax_kernel<<<1, 1024, 0, stream>>>(lg, wgt);
  wsum_kernel<<<32, 384, 0, stream>>>(wgt, h1, part);
  final2_kernel<<<1, 384, 0, stream>>>(part, Wv, ffws, out);
}